// Round 7
// baseline (249.391 us; speedup 1.0000x reference)
//
#include <hip/hip_runtime.h>
#include <math.h>

// Problem: B=32 batches, N=262144 points.
// Outputs (f32 flat): best_R [32*9] | best_t [32*3] | best_candidate [32]  (=416)
//
// Reference quirk: vec = Vh[..., :, -1] (last COLUMN of Vh) -> depends on f32
// LAPACK sgesdd sign conventions; we emulate sgesdd bit-faithfully.
// +/-t pairing: A(-t) = A(t)*diag(1,1,1,-1) and the f32 pipeline is exactly
// sign-covariant => vec(-t) = -vec(t) bit-exactly; one SVD serves 2 candidates.
// Round 7 = round 6 with the two compile errors fixed (reference-to-array
// params on gesdd3_pose; stray (void)X removed). No semantic change.
//
// ws layout (float units):
//   [0,1152)    R_cand[32][4][9]
//   [1152,1536) t_cand[32][4][3]
//   [1536,1664) kinv[32][4]
//   [1664,1792) scores[32][4] (int32)
//   [1792,1824) counts[32]   (int32)

#define NBATCH 32
#define USE_NEW_SLARTG 1   // LAPACK >=3.10 (modern OpenBLAS)

#define EPS4  5.9604645e-08f
#define UNFL4 1.1754944e-38f
#define TOL4  (10.0f * EPS4)

// ---------------- LAPACK-faithful f32 helpers (contract off) ----------------

__device__ __forceinline__ float sign_f(float a, float b) {
  return (b >= 0.0f) ? fabsf(a) : -fabsf(a);
}

__device__ __forceinline__ float slapy2f(float x, float y) {
#pragma clang fp contract(off)
  float xa = fabsf(x), ya = fabsf(y);
  float w = fmaxf(xa, ya), z = fminf(xa, ya);
  if (z == 0.0f) return w;
  float r = z / w;
  return w * sqrtf(1.0f + r * r);
}

__device__ __forceinline__ void slartg_(float f, float g, float* cs, float* sn, float* r) {
#pragma clang fp contract(off)
#if USE_NEW_SLARTG
  if (g == 0.0f) { *cs = 1.0f; *sn = 0.0f; *r = f; return; }
  if (f == 0.0f) { *cs = 0.0f; *sn = (g >= 0.0f) ? 1.0f : -1.0f; *r = fabsf(g); return; }
  float d = sqrtf(f * f + g * g);
  *cs = fabsf(f) / d;
  float rr = (f >= 0.0f) ? d : -d;
  *sn = g / rr;
  *r = rr;
#else
  if (g == 0.0f) { *cs = 1.0f; *sn = 0.0f; *r = f; return; }
  if (f == 0.0f) { *cs = 0.0f; *sn = 1.0f; *r = g; return; }
  float rr = sqrtf(f * f + g * g);
  float c = f / rr, s = g / rr;
  if (fabsf(f) > fabsf(g) && c < 0.0f) { c = -c; s = -s; rr = -rr; }
  *cs = c; *sn = s; *r = rr;
#endif
}

__device__ __forceinline__ void slas2_(float f, float g, float h, float* ssmin, float* ssmax) {
#pragma clang fp contract(off)
  float fa = fabsf(f), ga = fabsf(g), ha = fabsf(h);
  float fhmn = fminf(fa, ha), fhmx = fmaxf(fa, ha);
  if (fhmn == 0.0f) {
    *ssmin = 0.0f;
    if (fhmx == 0.0f) { *ssmax = ga; }
    else {
      float mx = fmaxf(fhmx, ga), mn = fminf(fhmx, ga);
      float r = mn / mx;
      *ssmax = mx * sqrtf(1.0f + r * r);
    }
  } else {
    if (ga < fhmx) {
      float as_ = 1.0f + fhmn / fhmx;
      float at = (fhmx - fhmn) / fhmx;
      float au = ga / fhmx; au = au * au;
      float c = 2.0f / (sqrtf(as_ * as_ + au) + sqrtf(at * at + au));
      *ssmin = fhmn * c;
      *ssmax = fhmx / c;
    } else {
      float au = fhmx / ga;
      if (au == 0.0f) { *ssmin = (fhmn * fhmx) / ga; *ssmax = ga; }
      else {
        float as_ = 1.0f + fhmn / fhmx;
        float at = (fhmx - fhmn) / fhmx;
        float aas = as_ * au, aat = at * au;
        float c = 1.0f / (sqrtf(1.0f + aas * aas) + sqrtf(1.0f + aat * aat));
        float sm = (fhmn * c) * au;
        *ssmin = sm + sm;
        *ssmax = ga / (c + c);
      }
    }
  }
}

__device__ __forceinline__ void slasv2_(float f, float g, float h, float* ssmin, float* ssmax,
                        float* snr, float* csr, float* snl, float* csl) {
#pragma clang fp contract(off)
  const float EPS = EPS4;
  float ft = f, fa = fabsf(f), ht = h, ha = fabsf(h);
  int pmax = 1;
  bool swap_ = (ha > fa);
  if (swap_) {
    pmax = 3;
    float t = ft; ft = ht; ht = t;
    t = fa; fa = ha; ha = t;
  }
  float gt = g, ga = fabsf(g);
  float clt = 0.f, crt = 0.f, slt = 0.f, srt = 0.f;
  if (ga == 0.0f) {
    *ssmin = ha; *ssmax = fa;
    clt = 1.0f; crt = 1.0f; slt = 0.0f; srt = 0.0f;
  } else {
    bool gasmal = true;
    if (ga > fa) {
      pmax = 2;
      if ((fa / ga) < EPS) {
        gasmal = false;
        *ssmax = ga;
        if (ha > 1.0f) *ssmin = fa / (ga / ha);
        else *ssmin = (fa / ga) * ha;
        clt = 1.0f; slt = ht / gt; srt = 1.0f; crt = ft / gt;
      }
    }
    if (gasmal) {
      float dd = fa - ha;
      float l;
      if (dd == fa) l = 1.0f; else l = dd / fa;
      float mm_ = gt / ft;
      float t = 2.0f - l;
      float mm = mm_ * mm_, tt = t * t;
      float s = sqrtf(tt + mm);
      float r;
      if (l == 0.0f) r = fabsf(mm_); else r = sqrtf(l * l + mm);
      float a = 0.5f * (s + r);
      *ssmin = ha / a;
      *ssmax = fa * a;
      if (mm == 0.0f) {
        if (l == 0.0f) t = sign_f(2.0f, ft) * sign_f(1.0f, gt);
        else t = gt / sign_f(dd, ft) + mm_ / t;
      } else {
        t = (mm_ / (s + t) + mm_ / (r + l)) * (1.0f + a);
      }
      float l2 = sqrtf(t * t + 4.0f);
      crt = 2.0f / l2;
      srt = t / l2;
      clt = (crt + srt * mm_) / a;
      slt = (ht / ft) * srt / a;
    }
  }
  if (swap_) { *csl = srt; *snl = crt; *csr = slt; *snr = clt; }
  else { *csl = clt; *snl = slt; *csr = crt; *snr = srt; }
  float tsign = 1.0f;
  if (pmax == 1) tsign = sign_f(1.0f, *csr) * sign_f(1.0f, *csl) * sign_f(1.0f, f);
  if (pmax == 2) tsign = sign_f(1.0f, *snr) * sign_f(1.0f, *csl) * sign_f(1.0f, g);
  if (pmax == 3) tsign = sign_f(1.0f, *snr) * sign_f(1.0f, *snl) * sign_f(1.0f, h);
  *ssmax = sign_f(*ssmax, tsign);
  *ssmin = sign_f(*ssmin, tsign * sign_f(1.0f, f) * sign_f(1.0f, h));
}

// =============== static (register-resident) n=3 sbdsqr with U+VT (pose) =====
// Mechanical unrolling of the generic sbdsqr (n=3): all indices compile-time.

__device__ __forceinline__ void sv3_chase(float (&d)[3], float (&e)[2],
                                          float (&vt)[3][3], float (&u)[3][3],
                                          float thresh, int& iter, int& oldll,
                                          int& oldm, int& idir, float smax) {
#pragma clang fp contract(off)
  // LL=1, M=3
  if (1 > oldm || 3 < oldll)
    idir = (fabsf(d[0]) >= fabsf(d[2])) ? 1 : 2;

  bool deflated = false;
  float sminl = 0.0f;
  if (idir == 1) {
    if (fabsf(e[1]) <= TOL4 * fabsf(d[2])) { e[1] = 0.0f; return; }
    float mu = fabsf(d[0]); sminl = mu;
    if (fabsf(e[0]) <= TOL4 * mu) { e[0] = 0.0f; deflated = true; }
    else {
      mu = fabsf(d[1]) * (mu / (mu + fabsf(e[0])));
      if (mu < sminl) sminl = mu;
      if (fabsf(e[1]) <= TOL4 * mu) { e[1] = 0.0f; deflated = true; }
      else {
        mu = fabsf(d[2]) * (mu / (mu + fabsf(e[1])));
        if (mu < sminl) sminl = mu;
      }
    }
  } else {
    if (fabsf(e[0]) <= TOL4 * fabsf(d[0])) { e[0] = 0.0f; return; }
    float mu = fabsf(d[2]); sminl = mu;
    if (fabsf(e[1]) <= TOL4 * mu) { e[1] = 0.0f; deflated = true; }
    else {
      mu = fabsf(d[1]) * (mu / (mu + fabsf(e[1])));
      if (mu < sminl) sminl = mu;
      if (fabsf(e[0]) <= TOL4 * mu) { e[0] = 0.0f; deflated = true; }
      else {
        mu = fabsf(d[0]) * (mu / (mu + fabsf(e[0])));
        if (mu < sminl) sminl = mu;
      }
    }
  }
  if (deflated) return;
  oldll = 1; oldm = 3;

  float shift = 0.0f, rdum;
  if (!(3.0f * TOL4 * (sminl / smax) <= fmaxf(EPS4, 0.01f * TOL4))) {
    float sll;
    if (idir == 1) { sll = fabsf(d[0]); slas2_(d[1], e[1], d[2], &shift, &rdum); }
    else { sll = fabsf(d[2]); slas2_(d[0], e[0], d[1], &shift, &rdum); }
    if (sll > 0.0f) {
      float q = shift / sll;
      if (q * q < EPS4) shift = 0.0f;
    }
  }
  iter += 2;

  if (shift == 0.0f) {
    if (idir == 1) {
      float cs = 1.0f, oldcs = 1.0f, sn = 0.0f, oldsn = 0.0f, r = 0.0f;
      float c1, s1, c2, s2, rr;
      // i = 1
      slartg_(d[0] * cs, e[0], &c1, &s1, &r); cs = c1; sn = s1;
      slartg_(oldcs * r, d[1] * sn, &c2, &s2, &rr); oldcs = c2; oldsn = s2;
      d[0] = rr;
#pragma unroll
      for (int k = 0; k < 3; k++) {
        float x = vt[0][k], y = vt[1][k];
        vt[0][k] = cs * x + sn * y; vt[1][k] = cs * y - sn * x;
      }
#pragma unroll
      for (int k = 0; k < 3; k++) {
        float x = u[k][0], y = u[k][1];
        u[k][0] = oldcs * x + oldsn * y; u[k][1] = oldcs * y - oldsn * x;
      }
      // i = 2
      slartg_(d[1] * cs, e[1], &c1, &s1, &r); cs = c1; sn = s1;
      e[0] = oldsn * r;
      slartg_(oldcs * r, d[2] * sn, &c2, &s2, &rr); oldcs = c2; oldsn = s2;
      d[1] = rr;
#pragma unroll
      for (int k = 0; k < 3; k++) {
        float x = vt[1][k], y = vt[2][k];
        vt[1][k] = cs * x + sn * y; vt[2][k] = cs * y - sn * x;
      }
#pragma unroll
      for (int k = 0; k < 3; k++) {
        float x = u[k][1], y = u[k][2];
        u[k][1] = oldcs * x + oldsn * y; u[k][2] = oldcs * y - oldsn * x;
      }
      float h = d[2] * cs;
      d[2] = h * oldcs;
      e[1] = h * oldsn;
      if (fabsf(e[1]) <= thresh) e[1] = 0.0f;
    } else {
      float cs = 1.0f, oldcs = 1.0f, sn = 0.0f, oldsn = 0.0f, r = 0.0f;
      float c1, s1, c2, s2, rr;
      // i = 3
      slartg_(d[2] * cs, e[1], &c1, &s1, &r); cs = c1; sn = s1;
      slartg_(oldcs * r, d[1] * sn, &c2, &s2, &rr); oldcs = c2; oldsn = s2;
      d[2] = rr;
#pragma unroll
      for (int k = 0; k < 3; k++) {
        float x = u[k][2], y = u[k][1];
        u[k][2] = cs * x + sn * y; u[k][1] = cs * y - sn * x;
      }
#pragma unroll
      for (int k = 0; k < 3; k++) {
        float x = vt[2][k], y = vt[1][k];
        vt[2][k] = oldcs * x + oldsn * y; vt[1][k] = oldcs * y - oldsn * x;
      }
      // i = 2
      slartg_(d[1] * cs, e[0], &c1, &s1, &r); cs = c1; sn = s1;
      e[1] = oldsn * r;
      slartg_(oldcs * r, d[0] * sn, &c2, &s2, &rr); oldcs = c2; oldsn = s2;
      d[1] = rr;
#pragma unroll
      for (int k = 0; k < 3; k++) {
        float x = u[k][1], y = u[k][0];
        u[k][1] = cs * x + sn * y; u[k][0] = cs * y - sn * x;
      }
#pragma unroll
      for (int k = 0; k < 3; k++) {
        float x = vt[1][k], y = vt[0][k];
        vt[1][k] = oldcs * x + oldsn * y; vt[0][k] = oldcs * y - oldsn * x;
      }
      float h = d[0] * cs;
      d[0] = h * oldcs;
      e[0] = h * oldsn;
      if (fabsf(e[0]) <= thresh) e[0] = 0.0f;
    }
  } else {
    if (idir == 1) {
      float f = (fabsf(d[0]) - shift) * (sign_f(1.0f, d[0]) + shift / d[0]);
      float g = e[0];
      float cosr, sinr, cosl, sinl, r, rr;
      // i = 1
      slartg_(f, g, &cosr, &sinr, &r);
      f = cosr * d[0] + sinr * e[0];
      e[0] = cosr * e[0] - sinr * d[0];
      g = sinr * d[1];
      d[1] = cosr * d[1];
      slartg_(f, g, &cosl, &sinl, &rr);
      d[0] = rr;
      f = cosl * e[0] + sinl * d[1];
      d[1] = cosl * d[1] - sinl * e[0];
      g = sinl * e[1];       // i < M-1
      e[1] = cosl * e[1];
#pragma unroll
      for (int k = 0; k < 3; k++) {
        float x = vt[0][k], y = vt[1][k];
        vt[0][k] = cosr * x + sinr * y; vt[1][k] = cosr * y - sinr * x;
      }
#pragma unroll
      for (int k = 0; k < 3; k++) {
        float x = u[k][0], y = u[k][1];
        u[k][0] = cosl * x + sinl * y; u[k][1] = cosl * y - sinl * x;
      }
      // i = 2
      slartg_(f, g, &cosr, &sinr, &r);
      e[0] = r;
      f = cosr * d[1] + sinr * e[1];
      e[1] = cosr * e[1] - sinr * d[1];
      g = sinr * d[2];
      d[2] = cosr * d[2];
      slartg_(f, g, &cosl, &sinl, &rr);
      d[1] = rr;
      f = cosl * e[1] + sinl * d[2];
      d[2] = cosl * d[2] - sinl * e[1];
#pragma unroll
      for (int k = 0; k < 3; k++) {
        float x = vt[1][k], y = vt[2][k];
        vt[1][k] = cosr * x + sinr * y; vt[2][k] = cosr * y - sinr * x;
      }
#pragma unroll
      for (int k = 0; k < 3; k++) {
        float x = u[k][1], y = u[k][2];
        u[k][1] = cosl * x + sinl * y; u[k][2] = cosl * y - sinl * x;
      }
      e[1] = f;
      if (fabsf(e[1]) <= thresh) e[1] = 0.0f;
    } else {
      float f = (fabsf(d[2]) - shift) * (sign_f(1.0f, d[2]) + shift / d[2]);
      float g = e[1];
      float cosr, sinr, cosl, sinl, r, rr;
      // i = 3
      slartg_(f, g, &cosr, &sinr, &r);
      f = cosr * d[2] + sinr * e[1];
      e[1] = cosr * e[1] - sinr * d[2];
      g = sinr * d[1];
      d[1] = cosr * d[1];
      slartg_(f, g, &cosl, &sinl, &rr);
      d[2] = rr;
      f = cosl * e[1] + sinl * d[1];
      d[1] = cosl * d[1] - sinl * e[1];
      g = sinl * e[0];       // i > LL+1
      e[0] = cosl * e[0];
#pragma unroll
      for (int k = 0; k < 3; k++) {
        float x = u[k][2], y = u[k][1];
        u[k][2] = cosr * x + sinr * y; u[k][1] = cosr * y - sinr * x;
      }
#pragma unroll
      for (int k = 0; k < 3; k++) {
        float x = vt[2][k], y = vt[1][k];
        vt[2][k] = cosl * x + sinl * y; vt[1][k] = cosl * y - sinl * x;
      }
      // i = 2
      slartg_(f, g, &cosr, &sinr, &r);
      e[1] = r;
      f = cosr * d[1] + sinr * e[0];
      e[0] = cosr * e[0] - sinr * d[1];
      g = sinr * d[0];
      d[0] = cosr * d[0];
      slartg_(f, g, &cosl, &sinl, &rr);
      d[1] = rr;
      f = cosl * e[0] + sinl * d[0];
      d[0] = cosl * d[0] - sinl * e[0];
#pragma unroll
      for (int k = 0; k < 3; k++) {
        float x = u[k][1], y = u[k][0];
        u[k][1] = cosr * x + sinr * y; u[k][0] = cosr * y - sinr * x;
      }
#pragma unroll
      for (int k = 0; k < 3; k++) {
        float x = vt[1][k], y = vt[0][k];
        vt[1][k] = cosl * x + sinl * y; vt[0][k] = cosl * y - sinl * x;
      }
      e[0] = f;
      if (fabsf(e[0]) <= thresh) e[0] = 0.0f;
    }
  }
}

__device__ __forceinline__ void sv3_iter3(float (&d)[3], float (&e)[2],
                                          float (&vt)[3][3], float (&u)[3][3],
                                          float thresh, int& m, int& iter,
                                          int& oldll, int& oldm, int& idir) {
#pragma clang fp contract(off)
  float smax = fabsf(d[2]);
  int ll = 0;
  bool split = false;
  // lll=1 -> ll=2
  if (fabsf(e[1]) <= thresh) { split = true; ll = 2; }
  else {
    smax = fmaxf(smax, fmaxf(fabsf(d[1]), fabsf(e[1])));
    // lll=2 -> ll=1
    if (fabsf(e[0]) <= thresh) { split = true; ll = 1; }
    else {
      smax = fmaxf(smax, fmaxf(fabsf(d[0]), fabsf(e[0])));
      ll = 1;
    }
  }
  if (split) {
    if (ll == 2) { e[1] = 0.0f; m = 2; return; }  // ll == m-1
    // ll==1: zero e[0], ll -> 2 == m-1 -> 2x2 on (d[1],e[1],d[2])
    e[0] = 0.0f;
    float sigmn, sigmx, sinr, cosr, sinl, cosl;
    slasv2_(d[1], e[1], d[2], &sigmn, &sigmx, &sinr, &cosr, &sinl, &cosl);
    d[1] = sigmx; e[1] = 0.0f; d[2] = sigmn;
#pragma unroll
    for (int k = 0; k < 3; k++) {
      float x = vt[1][k], y = vt[2][k];
      vt[1][k] = cosr * x + sinr * y; vt[2][k] = cosr * y - sinr * x;
    }
#pragma unroll
    for (int k = 0; k < 3; k++) {
      float x = u[k][1], y = u[k][2];
      u[k][1] = cosl * x + sinl * y; u[k][2] = cosl * y - sinl * x;
    }
    m = 1;
    return;
  }
  sv3_chase(d, e, vt, u, thresh, iter, oldll, oldm, idir, smax);
}

__device__ __forceinline__ void sv3_iter2(float (&d)[3], float (&e)[2],
                                          float (&vt)[3][3], float (&u)[3][3],
                                          float thresh, int& m) {
#pragma clang fp contract(off)
  if (fabsf(e[0]) <= thresh) { e[0] = 0.0f; m = 1; return; }
  float sigmn, sigmx, sinr, cosr, sinl, cosl;
  slasv2_(d[0], e[0], d[1], &sigmn, &sigmx, &sinr, &cosr, &sinl, &cosl);
  d[0] = sigmx; e[0] = 0.0f; d[1] = sigmn;
#pragma unroll
  for (int k = 0; k < 3; k++) {
    float x = vt[0][k], y = vt[1][k];
    vt[0][k] = cosr * x + sinr * y; vt[1][k] = cosr * y - sinr * x;
  }
#pragma unroll
  for (int k = 0; k < 3; k++) {
    float x = u[k][0], y = u[k][1];
    u[k][0] = cosl * x + sinl * y; u[k][1] = cosl * y - sinl * x;
  }
  m = 0;
}

// Full f32 sgesdd emulation for n=3 (jobz='A'): sgebd2 -> static sbdsqr -> Q/P.
__device__ void gesdd3_pose(const float E[9], float (&u)[3][3], float (&vt)[3][3]) {
#pragma clang fp contract(off)
  float a[3][3];
#pragma unroll
  for (int i = 0; i < 3; i++)
#pragma unroll
    for (int j = 0; j < 3; j++) a[i][j] = E[i * 3 + j];
  float d[3], e[2], tauq[3], taup[2];

  // ---- sgebd2 n=3 ----
  {
    float alpha = a[0][0];
    float ss = a[1][0] * a[1][0] + a[2][0] * a[2][0];
    if (ss == 0.0f) { tauq[0] = 0.0f; d[0] = alpha; }
    else {
      float xnorm = sqrtf(ss);
      float beta = -sign_f(slapy2f(alpha, xnorm), alpha);
      tauq[0] = (beta - alpha) / beta;
      float scal = 1.0f / (alpha - beta);
      a[1][0] *= scal; a[2][0] *= scal;
      d[0] = beta;
    }
#pragma unroll
    for (int c = 1; c < 3; c++) {
      float w = (a[0][c] + a[1][0] * a[1][c]) + a[2][0] * a[2][c];
      float tw = tauq[0] * w;
      a[0][c] -= tw; a[1][c] -= tw * a[1][0]; a[2][c] -= tw * a[2][0];
    }
    float alpha2 = a[0][1];
    float ss2 = a[0][2] * a[0][2];
    if (ss2 == 0.0f) { taup[0] = 0.0f; e[0] = alpha2; }
    else {
      float xnorm = sqrtf(ss2);
      float beta = -sign_f(slapy2f(alpha2, xnorm), alpha2);
      taup[0] = (beta - alpha2) / beta;
      float scal = 1.0f / (alpha2 - beta);
      a[0][2] *= scal;
      e[0] = beta;
    }
#pragma unroll
    for (int r = 1; r < 3; r++) {
      float w = a[r][1] + a[r][2] * a[0][2];
      float tw = taup[0] * w;
      a[r][1] -= tw; a[r][2] -= tw * a[0][2];
    }
  }
  {
    float alpha = a[1][1];
    float ss = a[2][1] * a[2][1];
    if (ss == 0.0f) { tauq[1] = 0.0f; d[1] = alpha; }
    else {
      float xnorm = sqrtf(ss);
      float beta = -sign_f(slapy2f(alpha, xnorm), alpha);
      tauq[1] = (beta - alpha) / beta;
      float scal = 1.0f / (alpha - beta);
      a[2][1] *= scal;
      d[1] = beta;
    }
    {
      float w = a[1][2] + a[2][1] * a[2][2];
      float tw = tauq[1] * w;
      a[1][2] -= tw; a[2][2] -= tw * a[2][1];
    }
    // right HH at i=1: empty x -> taup[1]=0, e[1]=a[1][2]; apply no-op to r=2
    taup[1] = 0.0f; e[1] = a[1][2];
    {
      float w = a[2][2];
      float tw = taup[1] * w;
      a[2][2] -= tw;
    }
  }
  tauq[2] = 0.0f;
  d[2] = a[2][2];

#pragma unroll
  for (int i = 0; i < 3; i++)
#pragma unroll
    for (int j = 0; j < 3; j++) {
      vt[i][j] = (i == j) ? 1.0f : 0.0f;
      u[i][j] = (i == j) ? 1.0f : 0.0f;
    }

  // ---- static sbdsqr n=3 ----
  {
    float sminoa = fabsf(d[0]);
    if (sminoa != 0.0f) {
      float mu = sminoa;
      mu = fabsf(d[1]) * (mu / (mu + fabsf(e[0])));
      if (mu < sminoa) sminoa = mu;
      if (sminoa != 0.0f) {
        mu = fabsf(d[2]) * (mu / (mu + fabsf(e[1])));
        if (mu < sminoa) sminoa = mu;
      }
    }
    sminoa = sminoa / sqrtf(3.0f);
    float thresh = fmaxf(TOL4 * sminoa, 54.0f * UNFL4);
    int m = 3, iter = 0, oldll = -1, oldm = -1, idir = 0, guard = 0;
    while (guard++ < 500) {
      if (m <= 1 || iter > 54) break;
      if (m == 3) sv3_iter3(d, e, vt, u, thresh, m, iter, oldll, oldm, idir);
      else sv3_iter2(d, e, vt, u, thresh, m);
    }
  }

  // ---- make nonnegative ----
#pragma unroll
  for (int i = 0; i < 3; i++) {
    if (d[i] < 0.0f) {
      d[i] = -d[i];
#pragma unroll
      for (int k = 0; k < 3; k++) vt[i][k] = -vt[i][k];
    }
  }
  // ---- sort descending (LAPACK tie rule <=), 2 passes ----
  {
    int isub = 1; float smn = d[0];
    if (d[1] <= smn) { isub = 2; smn = d[1]; }
    if (d[2] <= smn) { isub = 3; smn = d[2]; }
    if (isub != 3) {
      if (isub == 1) {
        d[0] = d[2];
#pragma unroll
        for (int k = 0; k < 3; k++) { float t = vt[0][k]; vt[0][k] = vt[2][k]; vt[2][k] = t; }
#pragma unroll
        for (int k = 0; k < 3; k++) { float t = u[k][0]; u[k][0] = u[k][2]; u[k][2] = t; }
      } else {
        d[1] = d[2];
#pragma unroll
        for (int k = 0; k < 3; k++) { float t = vt[1][k]; vt[1][k] = vt[2][k]; vt[2][k] = t; }
#pragma unroll
        for (int k = 0; k < 3; k++) { float t = u[k][1]; u[k][1] = u[k][2]; u[k][2] = t; }
      }
      d[2] = smn;
    }
  }
  {
    int isub = 1; float smn = d[0];
    if (d[1] <= smn) { isub = 2; smn = d[1]; }
    if (isub != 2) {
      d[0] = d[1]; d[1] = smn;
#pragma unroll
      for (int k = 0; k < 3; k++) { float t = vt[0][k]; vt[0][k] = vt[1][k]; vt[1][k] = t; }
#pragma unroll
      for (int k = 0; k < 3; k++) { float t = u[k][0]; u[k][0] = u[k][1]; u[k][1] = t; }
    }
  }

  // ---- U := Q * U  (i = 2, 1, 0) ----
#pragma unroll
  for (int c = 0; c < 3; c++) {
    float w = u[2][c];
    float tw = tauq[2] * w;
    u[2][c] -= tw;
  }
#pragma unroll
  for (int c = 0; c < 3; c++) {
    float w = u[1][c] + a[2][1] * u[2][c];
    float tw = tauq[1] * w;
    u[1][c] -= tw; u[2][c] -= tw * a[2][1];
  }
#pragma unroll
  for (int c = 0; c < 3; c++) {
    float w = (u[0][c] + a[1][0] * u[1][c]) + a[2][0] * u[2][c];
    float tw = tauq[0] * w;
    u[0][c] -= tw; u[1][c] -= tw * a[1][0]; u[2][c] -= tw * a[2][0];
  }
  // ---- VT := VT * P^T  (i = 1, 0) ----
#pragma unroll
  for (int r = 0; r < 3; r++) {
    float w = vt[r][2];
    float tw = taup[1] * w;
    vt[r][2] -= tw;
  }
#pragma unroll
  for (int r = 0; r < 3; r++) {
    float w = vt[r][1] + vt[r][2] * a[0][2];
    float tw = taup[0] * w;
    vt[r][1] -= tw; vt[r][2] -= tw * a[0][2];
  }
}

__device__ __forceinline__ float det3f(const float M[3][3]) {
#pragma clang fp contract(off)
  return M[0][0] * (M[1][1] * M[2][2] - M[1][2] * M[2][1])
       - M[0][1] * (M[1][0] * M[2][2] - M[1][2] * M[2][0])
       + M[0][2] * (M[1][0] * M[2][1] - M[1][1] * M[2][0]);
}

// =============== static (register-resident) n=4 sgesdd, VT cols 1..3 ========
// (unchanged — bit-exact verified)

template <int LL, int M>
__device__ __forceinline__ void sv_chase(float (&d)[4], float (&e)[3], float (&vt)[4][4],
                                         float thresh, int& iter, int& oldll, int& oldm,
                                         int& idir, float smax) {
#pragma clang fp contract(off)
  if (LL > oldm || M < oldll)
    idir = (fabsf(d[LL - 1]) >= fabsf(d[M - 1])) ? 1 : 2;

  bool deflated = false;
  float sminl = 0.0f;
  if (idir == 1) {
    if (fabsf(e[M - 2]) <= TOL4 * fabsf(d[M - 1])) { e[M - 2] = 0.0f; return; }
    float mu = fabsf(d[LL - 1]); sminl = mu;
#pragma unroll
    for (int lll = LL; lll <= M - 1; lll++) {
      if (!deflated) {
        if (fabsf(e[lll - 1]) <= TOL4 * mu) { e[lll - 1] = 0.0f; deflated = true; }
        else {
          mu = fabsf(d[lll]) * (mu / (mu + fabsf(e[lll - 1])));
          if (mu < sminl) sminl = mu;
        }
      }
    }
  } else {
    if (fabsf(e[LL - 1]) <= TOL4 * fabsf(d[LL - 1])) { e[LL - 1] = 0.0f; return; }
    float mu = fabsf(d[M - 1]); sminl = mu;
#pragma unroll
    for (int lll = M - 1; lll >= LL; lll--) {
      if (!deflated) {
        if (fabsf(e[lll - 1]) <= TOL4 * mu) { e[lll - 1] = 0.0f; deflated = true; }
        else {
          mu = fabsf(d[lll - 1]) * (mu / (mu + fabsf(e[lll - 1])));
          if (mu < sminl) sminl = mu;
        }
      }
    }
  }
  if (deflated) return;
  oldll = LL; oldm = M;

  float shift = 0.0f, rdum;
  if (!(4.0f * TOL4 * (sminl / smax) <= fmaxf(EPS4, 0.01f * TOL4))) {
    float sll;
    if (idir == 1) { sll = fabsf(d[LL - 1]); slas2_(d[M - 2], e[M - 2], d[M - 1], &shift, &rdum); }
    else { sll = fabsf(d[M - 1]); slas2_(d[LL - 1], e[LL - 1], d[LL], &shift, &rdum); }
    if (sll > 0.0f) {
      float q = shift / sll;
      if (q * q < EPS4) shift = 0.0f;
    }
  }
  iter += M - LL;

  if (shift == 0.0f) {
    if (idir == 1) {
      float cs = 1.0f, oldcs = 1.0f, sn = 0.0f, oldsn = 0.0f, r = 0.0f;
#pragma unroll
      for (int i = LL; i <= M - 1; i++) {
        float c1, s1;
        slartg_(d[i - 1] * cs, e[i - 1], &c1, &s1, &r);
        cs = c1; sn = s1;
        if (i > LL) e[i - 2] = oldsn * r;
        float c2, s2, rr;
        slartg_(oldcs * r, d[i] * sn, &c2, &s2, &rr);
        oldcs = c2; oldsn = s2;
        d[i - 1] = rr;
#pragma unroll
        for (int k = 1; k < 4; k++) {
          float x = vt[i - 1][k], y = vt[i][k];
          vt[i - 1][k] = cs * x + sn * y; vt[i][k] = cs * y - sn * x;
        }
      }
      float h = d[M - 1] * cs;
      d[M - 1] = h * oldcs;
      e[M - 2] = h * oldsn;
      if (fabsf(e[M - 2]) <= thresh) e[M - 2] = 0.0f;
    } else {
      float cs = 1.0f, oldcs = 1.0f, sn = 0.0f, oldsn = 0.0f, r = 0.0f;
#pragma unroll
      for (int i = M; i >= LL + 1; i--) {
        float c1, s1;
        slartg_(d[i - 1] * cs, e[i - 2], &c1, &s1, &r);
        cs = c1; sn = s1;
        if (i < M) e[i - 1] = oldsn * r;
        float c2, s2, rr;
        slartg_(oldcs * r, d[i - 2] * sn, &c2, &s2, &rr);
        oldcs = c2; oldsn = s2;
        d[i - 1] = rr;
#pragma unroll
        for (int k = 1; k < 4; k++) {
          float x = vt[i - 1][k], y = vt[i - 2][k];
          vt[i - 1][k] = oldcs * x + oldsn * y; vt[i - 2][k] = oldcs * y - oldsn * x;
        }
      }
      float h = d[LL - 1] * cs;
      d[LL - 1] = h * oldcs;
      e[LL - 1] = h * oldsn;
      if (fabsf(e[LL - 1]) <= thresh) e[LL - 1] = 0.0f;
    }
  } else {
    if (idir == 1) {
      float f = (fabsf(d[LL - 1]) - shift) * (sign_f(1.0f, d[LL - 1]) + shift / d[LL - 1]);
      float g = e[LL - 1];
#pragma unroll
      for (int i = LL; i <= M - 1; i++) {
        float cosr, sinr, r;
        slartg_(f, g, &cosr, &sinr, &r);
        if (i > LL) e[i - 2] = r;
        f = cosr * d[i - 1] + sinr * e[i - 1];
        e[i - 1] = cosr * e[i - 1] - sinr * d[i - 1];
        g = sinr * d[i];
        d[i] = cosr * d[i];
        float cosl, sinl, rr;
        slartg_(f, g, &cosl, &sinl, &rr);
        d[i - 1] = rr;
        f = cosl * e[i - 1] + sinl * d[i];
        d[i] = cosl * d[i] - sinl * e[i - 1];
        if (i < M - 1) {
          g = sinl * e[i];
          e[i] = cosl * e[i];
        }
#pragma unroll
        for (int k = 1; k < 4; k++) {
          float x = vt[i - 1][k], y = vt[i][k];
          vt[i - 1][k] = cosr * x + sinr * y; vt[i][k] = cosr * y - sinr * x;
        }
      }
      e[M - 2] = f;
      if (fabsf(e[M - 2]) <= thresh) e[M - 2] = 0.0f;
    } else {
      float f = (fabsf(d[M - 1]) - shift) * (sign_f(1.0f, d[M - 1]) + shift / d[M - 1]);
      float g = e[M - 2];
#pragma unroll
      for (int i = M; i >= LL + 1; i--) {
        float cosr, sinr, r;
        slartg_(f, g, &cosr, &sinr, &r);
        if (i < M) e[i - 1] = r;
        f = cosr * d[i - 1] + sinr * e[i - 2];
        e[i - 2] = cosr * e[i - 2] - sinr * d[i - 1];
        g = sinr * d[i - 2];
        d[i - 2] = cosr * d[i - 2];
        float cosl, sinl, rr;
        slartg_(f, g, &cosl, &sinl, &rr);
        d[i - 1] = rr;
        f = cosl * e[i - 2] + sinl * d[i - 2];
        d[i - 2] = cosl * d[i - 2] - sinl * e[i - 2];
        if (i > LL + 1) {
          g = sinl * e[i - 3];
          e[i - 3] = cosl * e[i - 3];
        }
#pragma unroll
        for (int k = 1; k < 4; k++) {
          float x = vt[i - 1][k], y = vt[i - 2][k];
          vt[i - 1][k] = cosl * x + sinl * y; vt[i - 2][k] = cosl * y - sinl * x;
        }
      }
      e[LL - 1] = f;
      if (fabsf(e[LL - 1]) <= thresh) e[LL - 1] = 0.0f;
    }
  }
}

template <int M>
__device__ __forceinline__ void sv_iter(float (&d)[4], float (&e)[3], float (&vt)[4][4],
                                        float thresh, int& m, int& iter,
                                        int& oldll, int& oldm, int& idir) {
#pragma clang fp contract(off)
  float smax = fabsf(d[M - 1]);
  float smin = smax;
  int ll = 0;
  bool split = false;
#pragma unroll
  for (int lll = 1; lll <= M - 1; lll++) {
    if (!split) {
      const int llc = M - lll;
      float abss = fabsf(d[llc - 1]);
      float abse = fabsf(e[llc - 1]);
      if (abse <= thresh) { split = true; ll = llc; }
      else {
        if (abss < smin) smin = abss;
        float mx = fmaxf(abss, abse);
        if (mx > smax) smax = mx;
        ll = llc;
      }
    }
  }
  (void)smin;
  if (split) {
    if (ll == 1) e[0] = 0.0f;
    else if (M > 2 && ll == 2) e[1] = 0.0f;
    else if (M > 3) e[2] = 0.0f;
    if (ll == M - 1) { m = M - 1; return; }
    ll = ll + 1;
  } else {
    ll = 1;
  }
  if (ll == M - 1) {
    float sigmn, sigmx, sinr, cosr, sinl, cosl;
    slasv2_(d[M - 2], e[M - 2], d[M - 1], &sigmn, &sigmx, &sinr, &cosr, &sinl, &cosl);
    d[M - 2] = sigmx; e[M - 2] = 0.0f; d[M - 1] = sigmn;
#pragma unroll
    for (int k = 1; k < 4; k++) {
      float x = vt[M - 2][k], y = vt[M - 1][k];
      vt[M - 2][k] = cosr * x + sinr * y; vt[M - 1][k] = cosr * y - sinr * x;
    }
    m = M - 2;
    return;
  }
  if constexpr (M == 4) {
    if (ll == 2) sv_chase<2, 4>(d, e, vt, thresh, iter, oldll, oldm, idir, smax);
    else sv_chase<1, 4>(d, e, vt, thresh, iter, oldll, oldm, idir, smax);
  } else if constexpr (M == 3) {
    sv_chase<1, 3>(d, e, vt, thresh, iter, oldll, oldm, idir, smax);
  }
}

// Full f32 sgesdd emulation for n=4, returning vec = final VT[:,3].
// Phase-ordered convergence loop (m=4 -> 3 -> 2); per-lane op sequence is
// bit-identical to the mixed loop since m is monotone non-increasing.
__device__ __forceinline__ void gesdd4_vec(const float A0[16], float vec[4]) {
#pragma clang fp contract(off)
  float a[4][4];
#pragma unroll
  for (int i = 0; i < 4; i++)
#pragma unroll
    for (int j = 0; j < 4; j++) a[i][j] = A0[i * 4 + j];
  float d[4], e[3], tauq[4], taup[3];

  // ---- sgebd2 n=4 ----
#pragma unroll
  for (int i = 0; i < 4; i++) {
    float alpha = a[i][i];
    float ss = 0.0f;
#pragma unroll
    for (int r = i + 1; r < 4; r++) ss += a[r][i] * a[r][i];
    if (ss == 0.0f) { tauq[i] = 0.0f; d[i] = alpha; }
    else {
      float xnorm = sqrtf(ss);
      float beta = -sign_f(slapy2f(alpha, xnorm), alpha);
      tauq[i] = (beta - alpha) / beta;
      float scal = 1.0f / (alpha - beta);
#pragma unroll
      for (int r = i + 1; r < 4; r++) a[r][i] *= scal;
      d[i] = beta;
    }
#pragma unroll
    for (int c = i + 1; c < 4; c++) {
      float w = a[i][c];
#pragma unroll
      for (int r = i + 1; r < 4; r++) w += a[r][i] * a[r][c];
      float tw = tauq[i] * w;
      a[i][c] -= tw;
#pragma unroll
      for (int r = i + 1; r < 4; r++) a[r][c] -= tw * a[r][i];
    }
    if (i < 3) {
      float alpha2 = a[i][i + 1];
      float ss2 = 0.0f;
#pragma unroll
      for (int c = i + 2; c < 4; c++) ss2 += a[i][c] * a[i][c];
      if (ss2 == 0.0f) { taup[i] = 0.0f; e[i] = alpha2; }
      else {
        float xnorm = sqrtf(ss2);
        float beta = -sign_f(slapy2f(alpha2, xnorm), alpha2);
        taup[i] = (beta - alpha2) / beta;
        float scal = 1.0f / (alpha2 - beta);
#pragma unroll
        for (int c = i + 2; c < 4; c++) a[i][c] *= scal;
        e[i] = beta;
      }
#pragma unroll
      for (int r = i + 1; r < 4; r++) {
        float w = a[r][i + 1];
#pragma unroll
        for (int c = i + 2; c < 4; c++) w += a[r][c] * a[i][c];
        float tw = taup[i] * w;
        a[r][i + 1] -= tw;
#pragma unroll
        for (int c = i + 2; c < 4; c++) a[r][c] -= tw * a[i][c];
      }
    }
  }

  // ---- VT = I (cols 1..3 tracked) ----
  float vt[4][4];
#pragma unroll
  for (int i = 0; i < 4; i++)
#pragma unroll
    for (int k = 1; k < 4; k++) vt[i][k] = (i == k) ? 1.0f : 0.0f;

  // ---- thresh ----
  float sminoa = fabsf(d[0]);
  if (sminoa != 0.0f) {
    float mu = sminoa;
    bool zr = false;
#pragma unroll
    for (int i = 2; i <= 4; i++) {
      if (!zr) {
        mu = fabsf(d[i - 1]) * (mu / (mu + fabsf(e[i - 2])));
        if (mu < sminoa) sminoa = mu;
        if (sminoa == 0.0f) zr = true;
      }
    }
  }
  sminoa = sminoa / sqrtf(4.0f);
  float thresh = fmaxf(TOL4 * sminoa, 96.0f * UNFL4);
  const int maxit = 96;

  int m = 4, iter = 0, oldll = -1, oldm = -1, idir = 0;
  // phase m==4
  for (int g = 0; g < 300; g++) {
    bool act = (m == 4) && (iter <= maxit);
    if (!__any(act)) break;
    if (act) sv_iter<4>(d, e, vt, thresh, m, iter, oldll, oldm, idir);
  }
  // phase m==3
  for (int g = 0; g < 300; g++) {
    bool act = (m == 3) && (iter <= maxit);
    if (!__any(act)) break;
    if (act) sv_iter<3>(d, e, vt, thresh, m, iter, oldll, oldm, idir);
  }
  // phase m==2
  for (int g = 0; g < 300; g++) {
    bool act = (m == 2) && (iter <= maxit);
    if (!__any(act)) break;
    if (act) sv_iter<2>(d, e, vt, thresh, m, iter, oldll, oldm, idir);
  }

  // ---- make nonnegative ----
#pragma unroll
  for (int i = 0; i < 4; i++) {
    if (d[i] < 0.0f) {
      d[i] = -d[i];
#pragma unroll
      for (int k = 1; k < 4; k++) vt[i][k] = -vt[i][k];
    }
  }
  // ---- sort descending (LAPACK tie rule <=), 3 passes ----
  {
    int isub = 1; float smn = d[0];
    if (d[1] <= smn) { isub = 2; smn = d[1]; }
    if (d[2] <= smn) { isub = 3; smn = d[2]; }
    if (d[3] <= smn) { isub = 4; smn = d[3]; }
    if (isub != 4) {
      if (isub == 1) {
        d[0] = d[3];
#pragma unroll
        for (int k = 1; k < 4; k++) { float t = vt[0][k]; vt[0][k] = vt[3][k]; vt[3][k] = t; }
      } else if (isub == 2) {
        d[1] = d[3];
#pragma unroll
        for (int k = 1; k < 4; k++) { float t = vt[1][k]; vt[1][k] = vt[3][k]; vt[3][k] = t; }
      } else {
        d[2] = d[3];
#pragma unroll
        for (int k = 1; k < 4; k++) { float t = vt[2][k]; vt[2][k] = vt[3][k]; vt[3][k] = t; }
      }
      d[3] = smn;
    }
  }
  {
    int isub = 1; float smn = d[0];
    if (d[1] <= smn) { isub = 2; smn = d[1]; }
    if (d[2] <= smn) { isub = 3; smn = d[2]; }
    if (isub != 3) {
      if (isub == 1) {
        d[0] = d[2];
#pragma unroll
        for (int k = 1; k < 4; k++) { float t = vt[0][k]; vt[0][k] = vt[2][k]; vt[2][k] = t; }
      } else {
        d[1] = d[2];
#pragma unroll
        for (int k = 1; k < 4; k++) { float t = vt[1][k]; vt[1][k] = vt[2][k]; vt[2][k] = t; }
      }
      d[2] = smn;
    }
  }
  {
    int isub = 1; float smn = d[0];
    if (d[1] <= smn) { isub = 2; smn = d[1]; }
    if (isub != 2) {
      d[0] = d[1];
#pragma unroll
      for (int k = 1; k < 4; k++) { float t = vt[0][k]; vt[0][k] = vt[1][k]; vt[1][k] = t; }
      d[1] = smn;
    }
  }

  // ---- sormbr: VT := VT * P^T   (i=2 is a taup=0 no-op; then i=1, i=0) ----
#pragma unroll
  for (int r = 0; r < 4; r++) {
    float w = vt[r][2] + vt[r][3] * a[1][3];
    float tw = taup[1] * w;
    vt[r][2] -= tw;
    vt[r][3] -= tw * a[1][3];
  }
#pragma unroll
  for (int r = 0; r < 4; r++) {
    float w = (vt[r][1] + vt[r][2] * a[0][2]) + vt[r][3] * a[0][3];
    float tw = taup[0] * w;
    vt[r][1] -= tw;
    vt[r][2] -= tw * a[0][2];
    vt[r][3] -= tw * a[0][3];
  }

  vec[0] = vt[0][3]; vec[1] = vt[1][3]; vec[2] = vt[2][3]; vec[3] = vt[3][3];
}

// ---------------- Kernel 1: per-batch pose candidates (1 batch / block) ----

__global__ __launch_bounds__(64) void pose_kernel(const float* __restrict__ Fm,
                                                  const float* __restrict__ Km,
                                                  float* __restrict__ ws) {
  int b = blockIdx.x;
  if (threadIdx.x != 0 || b >= NBATCH) return;
  float* wsR = ws;
  float* wsT = ws + 1152;
  float* wsK = ws + 1536;
  int* scores = (int*)(ws + 1664);
  int* counts = (int*)(ws + 1792);
  for (int c = 0; c < 4; c++) scores[b * 4 + c] = 0;
  counts[b] = 0;
  {
#pragma clang fp contract(off)
    const float* F = Fm + b * 9;
    const float* K = Km + b * 9;
    float E[9];
    for (int i = 0; i < 3; i++) for (int l = 0; l < 3; l++) {
      float acc = 0.0f;
      for (int j = 0; j < 3; j++)
        for (int k = 0; k < 3; k++)
          acc += (K[j * 3 + i] * F[j * 3 + k]) * K[k * 3 + l];
      E[i * 3 + l] = acc;
    }
    float U[3][3], VT[3][3];
    gesdd3_pose(E, U, VT);
    float su = (det3f(U) < 0.0f) ? -1.0f : 1.0f;
    float sv = (det3f(VT) < 0.0f) ? -1.0f : 1.0f;
    for (int i = 0; i < 3; i++) for (int j = 0; j < 3; j++) { U[i][j] *= su; VT[i][j] *= sv; }
    float R1[3][3], R2[3][3];
    for (int r = 0; r < 3; r++) {
      float uw0 = U[r][1], uw1 = -U[r][0], uw2 = U[r][2];
      float vw0 = -U[r][1], vw1 = U[r][0];
      for (int c = 0; c < 3; c++) {
        R1[r][c] = (uw0 * VT[c][0] + uw1 * VT[c][1]) + uw2 * VT[c][2];
        R2[r][c] = (vw0 * VT[c][0] + vw1 * VT[c][1]) + uw2 * VT[c][2];
      }
    }
    float t0 = U[0][2], t1 = U[1][2], t2 = U[2][2];
    for (int c = 0; c < 4; c++) {
      const float (*R)[3] = (c < 2) ? R1 : R2;
      float sg = (c & 1) ? -1.0f : 1.0f;
      float* dst = wsR + (b * 4 + c) * 9;
      for (int i = 0; i < 3; i++) for (int j = 0; j < 3; j++) dst[i * 3 + j] = R[i][j];
      float* dt = wsT + (b * 4 + c) * 3;
      dt[0] = sg * t0; dt[1] = sg * t1; dt[2] = sg * t2;
    }
    const float fx = K[0], fy = K[4], cx = K[2], cy = K[5];
    float invfx = 1.0f / fx, invfy = 1.0f / fy;
    wsK[b * 4 + 0] = invfx;
    wsK[b * 4 + 1] = -(invfx * cx);
    wsK[b * 4 + 2] = invfy;
    wsK[b * 4 + 3] = -(invfy * cy);
  }
}

// ---------------- Kernel 2: per-(point, R-pair) cheirality ----------------
// 128-thread blocks, no LDS; per-wave ballot histogram (bidx is sorted, so
// waves are batch-uniform except at the <=31 batch boundaries).

__global__ __launch_bounds__(128) void score_kernel(const float* __restrict__ pts1,
                                                    const float* __restrict__ pts2,
                                                    const int* __restrict__ bidx,
                                                    float* __restrict__ ws,
                                                    int n_pts) {
  int tid = threadIdx.x;
  int gid = blockIdx.x * 128 + tid;
  int n = gid >> 1, pr = gid & 1;  // pr=0 -> cands {0,1}; pr=1 -> cands {2,3}
  bool active = (n < n_pts);
  bool f0 = false, f1 = false;
  int b = 0;
  if (active) {
    b = bidx[n];
    float x1 = pts1[2 * n], y1 = pts1[2 * n + 1];
    float x2 = pts2[2 * n], y2 = pts2[2 * n + 1];
    const float* kinv = ws + 1536 + b * 4;
    float invfx = kinv[0], k02 = kinv[1];
    float invfy = kinv[2], k12 = kinv[3];
    const float* R = ws + (b * 4 + 2 * pr) * 9;
    const float* t = ws + 1152 + (b * 4 + 2 * pr) * 3;
    float Am[16];
    float row2[4] = { R[6], R[7], R[8], t[2] };
    {
#pragma clang fp contract(off)
      float p1x = invfx * x1 + k02;
      float p1y = invfy * y1 + k12;
      float p2x = invfx * x2 + k02;
      float p2y = invfy * y2 + k12;
      float row0[4] = { R[0], R[1], R[2], t[0] };
      float row1[4] = { R[3], R[4], R[5], t[1] };
      Am[0] = -1.0f; Am[1] = 0.0f; Am[2] = p1x; Am[3] = 0.0f;
      Am[4] = 0.0f; Am[5] = -1.0f; Am[6] = p1y; Am[7] = 0.0f;
#pragma unroll
      for (int k = 0; k < 4; k++) {
        Am[8 + k] = p2x * row2[k] - row0[k];
        Am[12 + k] = p2y * row2[k] - row1[k];
      }
    }
    float vec[4];
    gesdd4_vec(Am, vec);
    {
#pragma clang fp contract(off)
      float v3 = vec[3];
      float X = vec[0] / v3, Y = vec[1] / v3, Z = vec[2] / v3;
      float p0 = row2[0] * X, p1 = row2[1] * Y, p2 = row2[2] * Z;
      float s = (p0 + p1) + p2;
      float t2 = row2[3];
      float z2a = s + t2;        // candidate 2*pr   (+t)
      float z2b = s + (-t2);     // candidate 2*pr+1 (-t)
      bool zpos = (Z > 0.0f);
      f0 = zpos && (z2a > 0.0f);
      f1 = zpos && (z2b > 0.0f);
    }
  }

  int* scores = (int*)(ws + 1664);
  int* counts = (int*)(ws + 1792);
  int lane = tid & 63;
  unsigned long long act_m = __ballot(active ? 1 : 0);
  if (act_m != 0ULL) {
    int b0 = __shfl(b, 0);  // lane 0 active whenever any lane is (tail-only inactivity)
    bool uni = __all((!active || (b == b0)) ? 1 : 0);
    if (uni) {
      unsigned long long mc = __ballot((active && pr == 0) ? 1 : 0);
      unsigned long long m0 = __ballot((f0 && pr == 0) ? 1 : 0);
      unsigned long long m1 = __ballot((f1 && pr == 0) ? 1 : 0);
      unsigned long long m2 = __ballot((f0 && pr == 1) ? 1 : 0);
      unsigned long long m3 = __ballot((f1 && pr == 1) ? 1 : 0);
      if (lane == 0) {
        if (mc) atomicAdd(&counts[b0], (int)__popcll(mc));
        if (m0) atomicAdd(&scores[b0 * 4 + 0], (int)__popcll(m0));
        if (m1) atomicAdd(&scores[b0 * 4 + 1], (int)__popcll(m1));
        if (m2) atomicAdd(&scores[b0 * 4 + 2], (int)__popcll(m2));
        if (m3) atomicAdd(&scores[b0 * 4 + 3], (int)__popcll(m3));
      }
    } else if (active) {
      if (pr == 0) atomicAdd(&counts[b], 1);
      if (f0) atomicAdd(&scores[b * 4 + 2 * pr], 1);
      if (f1) atomicAdd(&scores[b * 4 + 2 * pr + 1], 1);
    }
  }
}

// ---------------- Kernel 3: argmax + output ----------------

__global__ __launch_bounds__(64) void final_kernel(const float* __restrict__ ws,
                                                   float* __restrict__ out) {
  int b = threadIdx.x;
  if (b >= NBATCH) return;
  const int* scores = (const int*)(ws + 1664);
  const int* counts = (const int*)(ws + 1792);
  int best = 0, bs = scores[b * 4];
  for (int c = 1; c < 4; c++) {
    int sc = scores[b * 4 + c];
    if (sc > bs) { bs = sc; best = c; }   // np.argmax: first max
  }
  int cnt = counts[b];
  float has = (cnt > 0) ? 1.0f : 0.0f;
  const float* R = ws + (b * 4 + best) * 9;
  const float* t = ws + 1152 + (b * 4 + best) * 3;
  for (int k = 0; k < 9; k++) out[b * 9 + k] = R[k] * has;
  for (int k = 0; k < 3; k++) out[288 + b * 3 + k] = t[k] * has;
  out[384 + b] = (cnt > 0) ? (float)best : 0.0f;
}

// ---------------- Launch ----------------

extern "C" void kernel_launch(void* const* d_in, const int* in_sizes, int n_in,
                              void* d_out, int out_size, void* d_ws, size_t ws_size,
                              hipStream_t stream) {
  (void)n_in; (void)out_size; (void)ws_size;
  const float* F = (const float*)d_in[0];
  const float* K = (const float*)d_in[1];
  const float* p1 = (const float*)d_in[2];
  const float* p2 = (const float*)d_in[3];
  const int* bi = (const int*)d_in[4];
  int n_pts = in_sizes[4];
  float* ws = (float*)d_ws;
  float* out = (float*)d_out;

  pose_kernel<<<NBATCH, 64, 0, stream>>>(F, K, ws);
  int total = n_pts * 2;
  int blocks = (total + 127) / 128;
  score_kernel<<<blocks, 128, 0, stream>>>(p1, p2, bi, ws, n_pts);
  final_kernel<<<1, 64, 0, stream>>>(ws, out);
}

// Round 8
// 211.176 us; speedup vs baseline: 1.1810x; 1.1810x over previous
//
#include <hip/hip_runtime.h>
#include <math.h>

// Problem: B=32 batches, N=262144 points.
// Outputs (f32 flat): best_R [32*9] | best_t [32*3] | best_candidate [32]  (=416)
//
// Reference quirk: vec = Vh[..., :, -1] (last COLUMN of Vh) -> depends on f32
// LAPACK sgesdd sign conventions; we emulate sgesdd bit-faithfully.
// +/-t pairing: A(-t) = A(t)*diag(1,1,1,-1) and the f32 pipeline is exactly
// sign-covariant => vec(-t) = -vec(t) bit-exactly; one SVD serves 2 candidates.
// Round 8 = round-5 score_kernel (LDS staging + LDS histogram, 256 threads;
// measured 151us) + round-7 static register-resident pose kernel (measured
// non-score 69->43us). Unbundles round-7's regression (de-staging caused
// scattered global gathers -> VALUBusy 81->60%).
//
// ws layout (float units):
//   [0,1152)    R_cand[32][4][9]
//   [1152,1536) t_cand[32][4][3]
//   [1536,1664) kinv[32][4]
//   [1664,1792) scores[32][4] (int32)
//   [1792,1824) counts[32]   (int32)

#define NBATCH 32
#define USE_NEW_SLARTG 1   // LAPACK >=3.10 (modern OpenBLAS)

#define EPS4  5.9604645e-08f
#define UNFL4 1.1754944e-38f
#define TOL4  (10.0f * EPS4)

// ---------------- LAPACK-faithful f32 helpers (contract off) ----------------

__device__ __forceinline__ float sign_f(float a, float b) {
  return (b >= 0.0f) ? fabsf(a) : -fabsf(a);
}

__device__ __forceinline__ float slapy2f(float x, float y) {
#pragma clang fp contract(off)
  float xa = fabsf(x), ya = fabsf(y);
  float w = fmaxf(xa, ya), z = fminf(xa, ya);
  if (z == 0.0f) return w;
  float r = z / w;
  return w * sqrtf(1.0f + r * r);
}

__device__ __forceinline__ void slartg_(float f, float g, float* cs, float* sn, float* r) {
#pragma clang fp contract(off)
#if USE_NEW_SLARTG
  if (g == 0.0f) { *cs = 1.0f; *sn = 0.0f; *r = f; return; }
  if (f == 0.0f) { *cs = 0.0f; *sn = (g >= 0.0f) ? 1.0f : -1.0f; *r = fabsf(g); return; }
  float d = sqrtf(f * f + g * g);
  *cs = fabsf(f) / d;
  float rr = (f >= 0.0f) ? d : -d;
  *sn = g / rr;
  *r = rr;
#else
  if (g == 0.0f) { *cs = 1.0f; *sn = 0.0f; *r = f; return; }
  if (f == 0.0f) { *cs = 0.0f; *sn = 1.0f; *r = g; return; }
  float rr = sqrtf(f * f + g * g);
  float c = f / rr, s = g / rr;
  if (fabsf(f) > fabsf(g) && c < 0.0f) { c = -c; s = -s; rr = -rr; }
  *cs = c; *sn = s; *r = rr;
#endif
}

__device__ __forceinline__ void slas2_(float f, float g, float h, float* ssmin, float* ssmax) {
#pragma clang fp contract(off)
  float fa = fabsf(f), ga = fabsf(g), ha = fabsf(h);
  float fhmn = fminf(fa, ha), fhmx = fmaxf(fa, ha);
  if (fhmn == 0.0f) {
    *ssmin = 0.0f;
    if (fhmx == 0.0f) { *ssmax = ga; }
    else {
      float mx = fmaxf(fhmx, ga), mn = fminf(fhmx, ga);
      float r = mn / mx;
      *ssmax = mx * sqrtf(1.0f + r * r);
    }
  } else {
    if (ga < fhmx) {
      float as_ = 1.0f + fhmn / fhmx;
      float at = (fhmx - fhmn) / fhmx;
      float au = ga / fhmx; au = au * au;
      float c = 2.0f / (sqrtf(as_ * as_ + au) + sqrtf(at * at + au));
      *ssmin = fhmn * c;
      *ssmax = fhmx / c;
    } else {
      float au = fhmx / ga;
      if (au == 0.0f) { *ssmin = (fhmn * fhmx) / ga; *ssmax = ga; }
      else {
        float as_ = 1.0f + fhmn / fhmx;
        float at = (fhmx - fhmn) / fhmx;
        float aas = as_ * au, aat = at * au;
        float c = 1.0f / (sqrtf(1.0f + aas * aas) + sqrtf(1.0f + aat * aat));
        float sm = (fhmn * c) * au;
        *ssmin = sm + sm;
        *ssmax = ga / (c + c);
      }
    }
  }
}

__device__ __forceinline__ void slasv2_(float f, float g, float h, float* ssmin, float* ssmax,
                        float* snr, float* csr, float* snl, float* csl) {
#pragma clang fp contract(off)
  const float EPS = EPS4;
  float ft = f, fa = fabsf(f), ht = h, ha = fabsf(h);
  int pmax = 1;
  bool swap_ = (ha > fa);
  if (swap_) {
    pmax = 3;
    float t = ft; ft = ht; ht = t;
    t = fa; fa = ha; ha = t;
  }
  float gt = g, ga = fabsf(g);
  float clt = 0.f, crt = 0.f, slt = 0.f, srt = 0.f;
  if (ga == 0.0f) {
    *ssmin = ha; *ssmax = fa;
    clt = 1.0f; crt = 1.0f; slt = 0.0f; srt = 0.0f;
  } else {
    bool gasmal = true;
    if (ga > fa) {
      pmax = 2;
      if ((fa / ga) < EPS) {
        gasmal = false;
        *ssmax = ga;
        if (ha > 1.0f) *ssmin = fa / (ga / ha);
        else *ssmin = (fa / ga) * ha;
        clt = 1.0f; slt = ht / gt; srt = 1.0f; crt = ft / gt;
      }
    }
    if (gasmal) {
      float dd = fa - ha;
      float l;
      if (dd == fa) l = 1.0f; else l = dd / fa;
      float mm_ = gt / ft;
      float t = 2.0f - l;
      float mm = mm_ * mm_, tt = t * t;
      float s = sqrtf(tt + mm);
      float r;
      if (l == 0.0f) r = fabsf(mm_); else r = sqrtf(l * l + mm);
      float a = 0.5f * (s + r);
      *ssmin = ha / a;
      *ssmax = fa * a;
      if (mm == 0.0f) {
        if (l == 0.0f) t = sign_f(2.0f, ft) * sign_f(1.0f, gt);
        else t = gt / sign_f(dd, ft) + mm_ / t;
      } else {
        t = (mm_ / (s + t) + mm_ / (r + l)) * (1.0f + a);
      }
      float l2 = sqrtf(t * t + 4.0f);
      crt = 2.0f / l2;
      srt = t / l2;
      clt = (crt + srt * mm_) / a;
      slt = (ht / ft) * srt / a;
    }
  }
  if (swap_) { *csl = srt; *snl = crt; *csr = slt; *snr = clt; }
  else { *csl = clt; *snl = slt; *csr = crt; *snr = srt; }
  float tsign = 1.0f;
  if (pmax == 1) tsign = sign_f(1.0f, *csr) * sign_f(1.0f, *csl) * sign_f(1.0f, f);
  if (pmax == 2) tsign = sign_f(1.0f, *snr) * sign_f(1.0f, *csl) * sign_f(1.0f, g);
  if (pmax == 3) tsign = sign_f(1.0f, *snr) * sign_f(1.0f, *snl) * sign_f(1.0f, h);
  *ssmax = sign_f(*ssmax, tsign);
  *ssmin = sign_f(*ssmin, tsign * sign_f(1.0f, f) * sign_f(1.0f, h));
}

// =============== static (register-resident) n=3 sbdsqr with U+VT (pose) =====

__device__ __forceinline__ void sv3_chase(float (&d)[3], float (&e)[2],
                                          float (&vt)[3][3], float (&u)[3][3],
                                          float thresh, int& iter, int& oldll,
                                          int& oldm, int& idir, float smax) {
#pragma clang fp contract(off)
  // LL=1, M=3
  if (1 > oldm || 3 < oldll)
    idir = (fabsf(d[0]) >= fabsf(d[2])) ? 1 : 2;

  bool deflated = false;
  float sminl = 0.0f;
  if (idir == 1) {
    if (fabsf(e[1]) <= TOL4 * fabsf(d[2])) { e[1] = 0.0f; return; }
    float mu = fabsf(d[0]); sminl = mu;
    if (fabsf(e[0]) <= TOL4 * mu) { e[0] = 0.0f; deflated = true; }
    else {
      mu = fabsf(d[1]) * (mu / (mu + fabsf(e[0])));
      if (mu < sminl) sminl = mu;
      if (fabsf(e[1]) <= TOL4 * mu) { e[1] = 0.0f; deflated = true; }
      else {
        mu = fabsf(d[2]) * (mu / (mu + fabsf(e[1])));
        if (mu < sminl) sminl = mu;
      }
    }
  } else {
    if (fabsf(e[0]) <= TOL4 * fabsf(d[0])) { e[0] = 0.0f; return; }
    float mu = fabsf(d[2]); sminl = mu;
    if (fabsf(e[1]) <= TOL4 * mu) { e[1] = 0.0f; deflated = true; }
    else {
      mu = fabsf(d[1]) * (mu / (mu + fabsf(e[1])));
      if (mu < sminl) sminl = mu;
      if (fabsf(e[0]) <= TOL4 * mu) { e[0] = 0.0f; deflated = true; }
      else {
        mu = fabsf(d[0]) * (mu / (mu + fabsf(e[0])));
        if (mu < sminl) sminl = mu;
      }
    }
  }
  if (deflated) return;
  oldll = 1; oldm = 3;

  float shift = 0.0f, rdum;
  if (!(3.0f * TOL4 * (sminl / smax) <= fmaxf(EPS4, 0.01f * TOL4))) {
    float sll;
    if (idir == 1) { sll = fabsf(d[0]); slas2_(d[1], e[1], d[2], &shift, &rdum); }
    else { sll = fabsf(d[2]); slas2_(d[0], e[0], d[1], &shift, &rdum); }
    if (sll > 0.0f) {
      float q = shift / sll;
      if (q * q < EPS4) shift = 0.0f;
    }
  }
  iter += 2;

  if (shift == 0.0f) {
    if (idir == 1) {
      float cs = 1.0f, oldcs = 1.0f, sn = 0.0f, oldsn = 0.0f, r = 0.0f;
      float c1, s1, c2, s2, rr;
      // i = 1
      slartg_(d[0] * cs, e[0], &c1, &s1, &r); cs = c1; sn = s1;
      slartg_(oldcs * r, d[1] * sn, &c2, &s2, &rr); oldcs = c2; oldsn = s2;
      d[0] = rr;
#pragma unroll
      for (int k = 0; k < 3; k++) {
        float x = vt[0][k], y = vt[1][k];
        vt[0][k] = cs * x + sn * y; vt[1][k] = cs * y - sn * x;
      }
#pragma unroll
      for (int k = 0; k < 3; k++) {
        float x = u[k][0], y = u[k][1];
        u[k][0] = oldcs * x + oldsn * y; u[k][1] = oldcs * y - oldsn * x;
      }
      // i = 2
      slartg_(d[1] * cs, e[1], &c1, &s1, &r); cs = c1; sn = s1;
      e[0] = oldsn * r;
      slartg_(oldcs * r, d[2] * sn, &c2, &s2, &rr); oldcs = c2; oldsn = s2;
      d[1] = rr;
#pragma unroll
      for (int k = 0; k < 3; k++) {
        float x = vt[1][k], y = vt[2][k];
        vt[1][k] = cs * x + sn * y; vt[2][k] = cs * y - sn * x;
      }
#pragma unroll
      for (int k = 0; k < 3; k++) {
        float x = u[k][1], y = u[k][2];
        u[k][1] = oldcs * x + oldsn * y; u[k][2] = oldcs * y - oldsn * x;
      }
      float h = d[2] * cs;
      d[2] = h * oldcs;
      e[1] = h * oldsn;
      if (fabsf(e[1]) <= thresh) e[1] = 0.0f;
    } else {
      float cs = 1.0f, oldcs = 1.0f, sn = 0.0f, oldsn = 0.0f, r = 0.0f;
      float c1, s1, c2, s2, rr;
      // i = 3
      slartg_(d[2] * cs, e[1], &c1, &s1, &r); cs = c1; sn = s1;
      slartg_(oldcs * r, d[1] * sn, &c2, &s2, &rr); oldcs = c2; oldsn = s2;
      d[2] = rr;
#pragma unroll
      for (int k = 0; k < 3; k++) {
        float x = u[k][2], y = u[k][1];
        u[k][2] = cs * x + sn * y; u[k][1] = cs * y - sn * x;
      }
#pragma unroll
      for (int k = 0; k < 3; k++) {
        float x = vt[2][k], y = vt[1][k];
        vt[2][k] = oldcs * x + oldsn * y; vt[1][k] = oldcs * y - oldsn * x;
      }
      // i = 2
      slartg_(d[1] * cs, e[0], &c1, &s1, &r); cs = c1; sn = s1;
      e[1] = oldsn * r;
      slartg_(oldcs * r, d[0] * sn, &c2, &s2, &rr); oldcs = c2; oldsn = s2;
      d[1] = rr;
#pragma unroll
      for (int k = 0; k < 3; k++) {
        float x = u[k][1], y = u[k][0];
        u[k][1] = cs * x + sn * y; u[k][0] = cs * y - sn * x;
      }
#pragma unroll
      for (int k = 0; k < 3; k++) {
        float x = vt[1][k], y = vt[0][k];
        vt[1][k] = oldcs * x + oldsn * y; vt[0][k] = oldcs * y - oldsn * x;
      }
      float h = d[0] * cs;
      d[0] = h * oldcs;
      e[0] = h * oldsn;
      if (fabsf(e[0]) <= thresh) e[0] = 0.0f;
    }
  } else {
    if (idir == 1) {
      float f = (fabsf(d[0]) - shift) * (sign_f(1.0f, d[0]) + shift / d[0]);
      float g = e[0];
      float cosr, sinr, cosl, sinl, r, rr;
      // i = 1
      slartg_(f, g, &cosr, &sinr, &r);
      f = cosr * d[0] + sinr * e[0];
      e[0] = cosr * e[0] - sinr * d[0];
      g = sinr * d[1];
      d[1] = cosr * d[1];
      slartg_(f, g, &cosl, &sinl, &rr);
      d[0] = rr;
      f = cosl * e[0] + sinl * d[1];
      d[1] = cosl * d[1] - sinl * e[0];
      g = sinl * e[1];       // i < M-1
      e[1] = cosl * e[1];
#pragma unroll
      for (int k = 0; k < 3; k++) {
        float x = vt[0][k], y = vt[1][k];
        vt[0][k] = cosr * x + sinr * y; vt[1][k] = cosr * y - sinr * x;
      }
#pragma unroll
      for (int k = 0; k < 3; k++) {
        float x = u[k][0], y = u[k][1];
        u[k][0] = cosl * x + sinl * y; u[k][1] = cosl * y - sinl * x;
      }
      // i = 2
      slartg_(f, g, &cosr, &sinr, &r);
      e[0] = r;
      f = cosr * d[1] + sinr * e[1];
      e[1] = cosr * e[1] - sinr * d[1];
      g = sinr * d[2];
      d[2] = cosr * d[2];
      slartg_(f, g, &cosl, &sinl, &rr);
      d[1] = rr;
      f = cosl * e[1] + sinl * d[2];
      d[2] = cosl * d[2] - sinl * e[1];
#pragma unroll
      for (int k = 0; k < 3; k++) {
        float x = vt[1][k], y = vt[2][k];
        vt[1][k] = cosr * x + sinr * y; vt[2][k] = cosr * y - sinr * x;
      }
#pragma unroll
      for (int k = 0; k < 3; k++) {
        float x = u[k][1], y = u[k][2];
        u[k][1] = cosl * x + sinl * y; u[k][2] = cosl * y - sinl * x;
      }
      e[1] = f;
      if (fabsf(e[1]) <= thresh) e[1] = 0.0f;
    } else {
      float f = (fabsf(d[2]) - shift) * (sign_f(1.0f, d[2]) + shift / d[2]);
      float g = e[1];
      float cosr, sinr, cosl, sinl, r, rr;
      // i = 3
      slartg_(f, g, &cosr, &sinr, &r);
      f = cosr * d[2] + sinr * e[1];
      e[1] = cosr * e[1] - sinr * d[2];
      g = sinr * d[1];
      d[1] = cosr * d[1];
      slartg_(f, g, &cosl, &sinl, &rr);
      d[2] = rr;
      f = cosl * e[1] + sinl * d[1];
      d[1] = cosl * d[1] - sinl * e[1];
      g = sinl * e[0];       // i > LL+1
      e[0] = cosl * e[0];
#pragma unroll
      for (int k = 0; k < 3; k++) {
        float x = u[k][2], y = u[k][1];
        u[k][2] = cosr * x + sinr * y; u[k][1] = cosr * y - sinr * x;
      }
#pragma unroll
      for (int k = 0; k < 3; k++) {
        float x = vt[2][k], y = vt[1][k];
        vt[2][k] = cosl * x + sinl * y; vt[1][k] = cosl * y - sinl * x;
      }
      // i = 2
      slartg_(f, g, &cosr, &sinr, &r);
      e[1] = r;
      f = cosr * d[1] + sinr * e[0];
      e[0] = cosr * e[0] - sinr * d[1];
      g = sinr * d[0];
      d[0] = cosr * d[0];
      slartg_(f, g, &cosl, &sinl, &rr);
      d[1] = rr;
      f = cosl * e[0] + sinl * d[0];
      d[0] = cosl * d[0] - sinl * e[0];
#pragma unroll
      for (int k = 0; k < 3; k++) {
        float x = u[k][1], y = u[k][0];
        u[k][1] = cosr * x + sinr * y; u[k][0] = cosr * y - sinr * x;
      }
#pragma unroll
      for (int k = 0; k < 3; k++) {
        float x = vt[1][k], y = vt[0][k];
        vt[1][k] = cosl * x + sinl * y; vt[0][k] = cosl * y - sinl * x;
      }
      e[0] = f;
      if (fabsf(e[0]) <= thresh) e[0] = 0.0f;
    }
  }
}

__device__ __forceinline__ void sv3_iter3(float (&d)[3], float (&e)[2],
                                          float (&vt)[3][3], float (&u)[3][3],
                                          float thresh, int& m, int& iter,
                                          int& oldll, int& oldm, int& idir) {
#pragma clang fp contract(off)
  float smax = fabsf(d[2]);
  int ll = 0;
  bool split = false;
  // lll=1 -> ll=2
  if (fabsf(e[1]) <= thresh) { split = true; ll = 2; }
  else {
    smax = fmaxf(smax, fmaxf(fabsf(d[1]), fabsf(e[1])));
    // lll=2 -> ll=1
    if (fabsf(e[0]) <= thresh) { split = true; ll = 1; }
    else {
      smax = fmaxf(smax, fmaxf(fabsf(d[0]), fabsf(e[0])));
      ll = 1;
    }
  }
  if (split) {
    if (ll == 2) { e[1] = 0.0f; m = 2; return; }  // ll == m-1
    // ll==1: zero e[0], ll -> 2 == m-1 -> 2x2 on (d[1],e[1],d[2])
    e[0] = 0.0f;
    float sigmn, sigmx, sinr, cosr, sinl, cosl;
    slasv2_(d[1], e[1], d[2], &sigmn, &sigmx, &sinr, &cosr, &sinl, &cosl);
    d[1] = sigmx; e[1] = 0.0f; d[2] = sigmn;
#pragma unroll
    for (int k = 0; k < 3; k++) {
      float x = vt[1][k], y = vt[2][k];
      vt[1][k] = cosr * x + sinr * y; vt[2][k] = cosr * y - sinr * x;
    }
#pragma unroll
    for (int k = 0; k < 3; k++) {
      float x = u[k][1], y = u[k][2];
      u[k][1] = cosl * x + sinl * y; u[k][2] = cosl * y - sinl * x;
    }
    m = 1;
    return;
  }
  sv3_chase(d, e, vt, u, thresh, iter, oldll, oldm, idir, smax);
}

__device__ __forceinline__ void sv3_iter2(float (&d)[3], float (&e)[2],
                                          float (&vt)[3][3], float (&u)[3][3],
                                          float thresh, int& m) {
#pragma clang fp contract(off)
  if (fabsf(e[0]) <= thresh) { e[0] = 0.0f; m = 1; return; }
  float sigmn, sigmx, sinr, cosr, sinl, cosl;
  slasv2_(d[0], e[0], d[1], &sigmn, &sigmx, &sinr, &cosr, &sinl, &cosl);
  d[0] = sigmx; e[0] = 0.0f; d[1] = sigmn;
#pragma unroll
  for (int k = 0; k < 3; k++) {
    float x = vt[0][k], y = vt[1][k];
    vt[0][k] = cosr * x + sinr * y; vt[1][k] = cosr * y - sinr * x;
  }
#pragma unroll
  for (int k = 0; k < 3; k++) {
    float x = u[k][0], y = u[k][1];
    u[k][0] = cosl * x + sinl * y; u[k][1] = cosl * y - sinl * x;
  }
  m = 0;
}

// Full f32 sgesdd emulation for n=3 (jobz='A'): sgebd2 -> static sbdsqr -> Q/P.
__device__ void gesdd3_pose(const float E[9], float (&u)[3][3], float (&vt)[3][3]) {
#pragma clang fp contract(off)
  float a[3][3];
#pragma unroll
  for (int i = 0; i < 3; i++)
#pragma unroll
    for (int j = 0; j < 3; j++) a[i][j] = E[i * 3 + j];
  float d[3], e[2], tauq[3], taup[2];

  // ---- sgebd2 n=3 ----
  {
    float alpha = a[0][0];
    float ss = a[1][0] * a[1][0] + a[2][0] * a[2][0];
    if (ss == 0.0f) { tauq[0] = 0.0f; d[0] = alpha; }
    else {
      float xnorm = sqrtf(ss);
      float beta = -sign_f(slapy2f(alpha, xnorm), alpha);
      tauq[0] = (beta - alpha) / beta;
      float scal = 1.0f / (alpha - beta);
      a[1][0] *= scal; a[2][0] *= scal;
      d[0] = beta;
    }
#pragma unroll
    for (int c = 1; c < 3; c++) {
      float w = (a[0][c] + a[1][0] * a[1][c]) + a[2][0] * a[2][c];
      float tw = tauq[0] * w;
      a[0][c] -= tw; a[1][c] -= tw * a[1][0]; a[2][c] -= tw * a[2][0];
    }
    float alpha2 = a[0][1];
    float ss2 = a[0][2] * a[0][2];
    if (ss2 == 0.0f) { taup[0] = 0.0f; e[0] = alpha2; }
    else {
      float xnorm = sqrtf(ss2);
      float beta = -sign_f(slapy2f(alpha2, xnorm), alpha2);
      taup[0] = (beta - alpha2) / beta;
      float scal = 1.0f / (alpha2 - beta);
      a[0][2] *= scal;
      e[0] = beta;
    }
#pragma unroll
    for (int r = 1; r < 3; r++) {
      float w = a[r][1] + a[r][2] * a[0][2];
      float tw = taup[0] * w;
      a[r][1] -= tw; a[r][2] -= tw * a[0][2];
    }
  }
  {
    float alpha = a[1][1];
    float ss = a[2][1] * a[2][1];
    if (ss == 0.0f) { tauq[1] = 0.0f; d[1] = alpha; }
    else {
      float xnorm = sqrtf(ss);
      float beta = -sign_f(slapy2f(alpha, xnorm), alpha);
      tauq[1] = (beta - alpha) / beta;
      float scal = 1.0f / (alpha - beta);
      a[2][1] *= scal;
      d[1] = beta;
    }
    {
      float w = a[1][2] + a[2][1] * a[2][2];
      float tw = tauq[1] * w;
      a[1][2] -= tw; a[2][2] -= tw * a[2][1];
    }
    taup[1] = 0.0f; e[1] = a[1][2];
    {
      float w = a[2][2];
      float tw = taup[1] * w;
      a[2][2] -= tw;
    }
  }
  tauq[2] = 0.0f;
  d[2] = a[2][2];

#pragma unroll
  for (int i = 0; i < 3; i++)
#pragma unroll
    for (int j = 0; j < 3; j++) {
      vt[i][j] = (i == j) ? 1.0f : 0.0f;
      u[i][j] = (i == j) ? 1.0f : 0.0f;
    }

  // ---- static sbdsqr n=3 ----
  {
    float sminoa = fabsf(d[0]);
    if (sminoa != 0.0f) {
      float mu = sminoa;
      mu = fabsf(d[1]) * (mu / (mu + fabsf(e[0])));
      if (mu < sminoa) sminoa = mu;
      if (sminoa != 0.0f) {
        mu = fabsf(d[2]) * (mu / (mu + fabsf(e[1])));
        if (mu < sminoa) sminoa = mu;
      }
    }
    sminoa = sminoa / sqrtf(3.0f);
    float thresh = fmaxf(TOL4 * sminoa, 54.0f * UNFL4);
    int m = 3, iter = 0, oldll = -1, oldm = -1, idir = 0, guard = 0;
    while (guard++ < 500) {
      if (m <= 1 || iter > 54) break;
      if (m == 3) sv3_iter3(d, e, vt, u, thresh, m, iter, oldll, oldm, idir);
      else sv3_iter2(d, e, vt, u, thresh, m);
    }
  }

  // ---- make nonnegative ----
#pragma unroll
  for (int i = 0; i < 3; i++) {
    if (d[i] < 0.0f) {
      d[i] = -d[i];
#pragma unroll
      for (int k = 0; k < 3; k++) vt[i][k] = -vt[i][k];
    }
  }
  // ---- sort descending (LAPACK tie rule <=), 2 passes ----
  {
    int isub = 1; float smn = d[0];
    if (d[1] <= smn) { isub = 2; smn = d[1]; }
    if (d[2] <= smn) { isub = 3; smn = d[2]; }
    if (isub != 3) {
      if (isub == 1) {
        d[0] = d[2];
#pragma unroll
        for (int k = 0; k < 3; k++) { float t = vt[0][k]; vt[0][k] = vt[2][k]; vt[2][k] = t; }
#pragma unroll
        for (int k = 0; k < 3; k++) { float t = u[k][0]; u[k][0] = u[k][2]; u[k][2] = t; }
      } else {
        d[1] = d[2];
#pragma unroll
        for (int k = 0; k < 3; k++) { float t = vt[1][k]; vt[1][k] = vt[2][k]; vt[2][k] = t; }
#pragma unroll
        for (int k = 0; k < 3; k++) { float t = u[k][1]; u[k][1] = u[k][2]; u[k][2] = t; }
      }
      d[2] = smn;
    }
  }
  {
    int isub = 1; float smn = d[0];
    if (d[1] <= smn) { isub = 2; smn = d[1]; }
    if (isub != 2) {
      d[0] = d[1]; d[1] = smn;
#pragma unroll
      for (int k = 0; k < 3; k++) { float t = vt[0][k]; vt[0][k] = vt[1][k]; vt[1][k] = t; }
#pragma unroll
      for (int k = 0; k < 3; k++) { float t = u[k][0]; u[k][0] = u[k][1]; u[k][1] = t; }
    }
  }

  // ---- U := Q * U  (i = 2, 1, 0) ----
#pragma unroll
  for (int c = 0; c < 3; c++) {
    float w = u[2][c];
    float tw = tauq[2] * w;
    u[2][c] -= tw;
  }
#pragma unroll
  for (int c = 0; c < 3; c++) {
    float w = u[1][c] + a[2][1] * u[2][c];
    float tw = tauq[1] * w;
    u[1][c] -= tw; u[2][c] -= tw * a[2][1];
  }
#pragma unroll
  for (int c = 0; c < 3; c++) {
    float w = (u[0][c] + a[1][0] * u[1][c]) + a[2][0] * u[2][c];
    float tw = tauq[0] * w;
    u[0][c] -= tw; u[1][c] -= tw * a[1][0]; u[2][c] -= tw * a[2][0];
  }
  // ---- VT := VT * P^T  (i = 1, 0) ----
#pragma unroll
  for (int r = 0; r < 3; r++) {
    float w = vt[r][2];
    float tw = taup[1] * w;
    vt[r][2] -= tw;
  }
#pragma unroll
  for (int r = 0; r < 3; r++) {
    float w = vt[r][1] + vt[r][2] * a[0][2];
    float tw = taup[0] * w;
    vt[r][1] -= tw; vt[r][2] -= tw * a[0][2];
  }
}

__device__ __forceinline__ float det3f(const float M[3][3]) {
#pragma clang fp contract(off)
  return M[0][0] * (M[1][1] * M[2][2] - M[1][2] * M[2][1])
       - M[0][1] * (M[1][0] * M[2][2] - M[1][2] * M[2][0])
       + M[0][2] * (M[1][0] * M[2][1] - M[1][1] * M[2][0]);
}

// =============== static (register-resident) n=4 sgesdd, VT cols 1..3 ========

template <int LL, int M>
__device__ __forceinline__ void sv_chase(float (&d)[4], float (&e)[3], float (&vt)[4][4],
                                         float thresh, int& iter, int& oldll, int& oldm,
                                         int& idir, float smax) {
#pragma clang fp contract(off)
  if (LL > oldm || M < oldll)
    idir = (fabsf(d[LL - 1]) >= fabsf(d[M - 1])) ? 1 : 2;

  bool deflated = false;
  float sminl = 0.0f;
  if (idir == 1) {
    if (fabsf(e[M - 2]) <= TOL4 * fabsf(d[M - 1])) { e[M - 2] = 0.0f; return; }
    float mu = fabsf(d[LL - 1]); sminl = mu;
#pragma unroll
    for (int lll = LL; lll <= M - 1; lll++) {
      if (!deflated) {
        if (fabsf(e[lll - 1]) <= TOL4 * mu) { e[lll - 1] = 0.0f; deflated = true; }
        else {
          mu = fabsf(d[lll]) * (mu / (mu + fabsf(e[lll - 1])));
          if (mu < sminl) sminl = mu;
        }
      }
    }
  } else {
    if (fabsf(e[LL - 1]) <= TOL4 * fabsf(d[LL - 1])) { e[LL - 1] = 0.0f; return; }
    float mu = fabsf(d[M - 1]); sminl = mu;
#pragma unroll
    for (int lll = M - 1; lll >= LL; lll--) {
      if (!deflated) {
        if (fabsf(e[lll - 1]) <= TOL4 * mu) { e[lll - 1] = 0.0f; deflated = true; }
        else {
          mu = fabsf(d[lll - 1]) * (mu / (mu + fabsf(e[lll - 1])));
          if (mu < sminl) sminl = mu;
        }
      }
    }
  }
  if (deflated) return;
  oldll = LL; oldm = M;

  float shift = 0.0f, rdum;
  if (!(4.0f * TOL4 * (sminl / smax) <= fmaxf(EPS4, 0.01f * TOL4))) {
    float sll;
    if (idir == 1) { sll = fabsf(d[LL - 1]); slas2_(d[M - 2], e[M - 2], d[M - 1], &shift, &rdum); }
    else { sll = fabsf(d[M - 1]); slas2_(d[LL - 1], e[LL - 1], d[LL], &shift, &rdum); }
    if (sll > 0.0f) {
      float q = shift / sll;
      if (q * q < EPS4) shift = 0.0f;
    }
  }
  iter += M - LL;

  if (shift == 0.0f) {
    if (idir == 1) {
      float cs = 1.0f, oldcs = 1.0f, sn = 0.0f, oldsn = 0.0f, r = 0.0f;
#pragma unroll
      for (int i = LL; i <= M - 1; i++) {
        float c1, s1;
        slartg_(d[i - 1] * cs, e[i - 1], &c1, &s1, &r);
        cs = c1; sn = s1;
        if (i > LL) e[i - 2] = oldsn * r;
        float c2, s2, rr;
        slartg_(oldcs * r, d[i] * sn, &c2, &s2, &rr);
        oldcs = c2; oldsn = s2;
        d[i - 1] = rr;
#pragma unroll
        for (int k = 1; k < 4; k++) {
          float x = vt[i - 1][k], y = vt[i][k];
          vt[i - 1][k] = cs * x + sn * y; vt[i][k] = cs * y - sn * x;
        }
      }
      float h = d[M - 1] * cs;
      d[M - 1] = h * oldcs;
      e[M - 2] = h * oldsn;
      if (fabsf(e[M - 2]) <= thresh) e[M - 2] = 0.0f;
    } else {
      float cs = 1.0f, oldcs = 1.0f, sn = 0.0f, oldsn = 0.0f, r = 0.0f;
#pragma unroll
      for (int i = M; i >= LL + 1; i--) {
        float c1, s1;
        slartg_(d[i - 1] * cs, e[i - 2], &c1, &s1, &r);
        cs = c1; sn = s1;
        if (i < M) e[i - 1] = oldsn * r;
        float c2, s2, rr;
        slartg_(oldcs * r, d[i - 2] * sn, &c2, &s2, &rr);
        oldcs = c2; oldsn = s2;
        d[i - 1] = rr;
#pragma unroll
        for (int k = 1; k < 4; k++) {
          float x = vt[i - 1][k], y = vt[i - 2][k];
          vt[i - 1][k] = oldcs * x + oldsn * y; vt[i - 2][k] = oldcs * y - oldsn * x;
        }
      }
      float h = d[LL - 1] * cs;
      d[LL - 1] = h * oldcs;
      e[LL - 1] = h * oldsn;
      if (fabsf(e[LL - 1]) <= thresh) e[LL - 1] = 0.0f;
    }
  } else {
    if (idir == 1) {
      float f = (fabsf(d[LL - 1]) - shift) * (sign_f(1.0f, d[LL - 1]) + shift / d[LL - 1]);
      float g = e[LL - 1];
#pragma unroll
      for (int i = LL; i <= M - 1; i++) {
        float cosr, sinr, r;
        slartg_(f, g, &cosr, &sinr, &r);
        if (i > LL) e[i - 2] = r;
        f = cosr * d[i - 1] + sinr * e[i - 1];
        e[i - 1] = cosr * e[i - 1] - sinr * d[i - 1];
        g = sinr * d[i];
        d[i] = cosr * d[i];
        float cosl, sinl, rr;
        slartg_(f, g, &cosl, &sinl, &rr);
        d[i - 1] = rr;
        f = cosl * e[i - 1] + sinl * d[i];
        d[i] = cosl * d[i] - sinl * e[i - 1];
        if (i < M - 1) {
          g = sinl * e[i];
          e[i] = cosl * e[i];
        }
#pragma unroll
        for (int k = 1; k < 4; k++) {
          float x = vt[i - 1][k], y = vt[i][k];
          vt[i - 1][k] = cosr * x + sinr * y; vt[i][k] = cosr * y - sinr * x;
        }
      }
      e[M - 2] = f;
      if (fabsf(e[M - 2]) <= thresh) e[M - 2] = 0.0f;
    } else {
      float f = (fabsf(d[M - 1]) - shift) * (sign_f(1.0f, d[M - 1]) + shift / d[M - 1]);
      float g = e[M - 2];
#pragma unroll
      for (int i = M; i >= LL + 1; i--) {
        float cosr, sinr, r;
        slartg_(f, g, &cosr, &sinr, &r);
        if (i < M) e[i - 1] = r;
        f = cosr * d[i - 1] + sinr * e[i - 2];
        e[i - 2] = cosr * e[i - 2] - sinr * d[i - 1];
        g = sinr * d[i - 2];
        d[i - 2] = cosr * d[i - 2];
        float cosl, sinl, rr;
        slartg_(f, g, &cosl, &sinl, &rr);
        d[i - 1] = rr;
        f = cosl * e[i - 2] + sinl * d[i - 2];
        d[i - 2] = cosl * d[i - 2] - sinl * e[i - 2];
        if (i > LL + 1) {
          g = sinl * e[i - 3];
          e[i - 3] = cosl * e[i - 3];
        }
#pragma unroll
        for (int k = 1; k < 4; k++) {
          float x = vt[i - 1][k], y = vt[i - 2][k];
          vt[i - 1][k] = cosl * x + sinl * y; vt[i - 2][k] = cosl * y - sinl * x;
        }
      }
      e[LL - 1] = f;
      if (fabsf(e[LL - 1]) <= thresh) e[LL - 1] = 0.0f;
    }
  }
}

template <int M>
__device__ __forceinline__ void sv_iter(float (&d)[4], float (&e)[3], float (&vt)[4][4],
                                        float thresh, int& m, int& iter,
                                        int& oldll, int& oldm, int& idir) {
#pragma clang fp contract(off)
  float smax = fabsf(d[M - 1]);
  float smin = smax;
  int ll = 0;
  bool split = false;
#pragma unroll
  for (int lll = 1; lll <= M - 1; lll++) {
    if (!split) {
      const int llc = M - lll;
      float abss = fabsf(d[llc - 1]);
      float abse = fabsf(e[llc - 1]);
      if (abse <= thresh) { split = true; ll = llc; }
      else {
        if (abss < smin) smin = abss;
        float mx = fmaxf(abss, abse);
        if (mx > smax) smax = mx;
        ll = llc;
      }
    }
  }
  (void)smin;
  if (split) {
    if (ll == 1) e[0] = 0.0f;
    else if (M > 2 && ll == 2) e[1] = 0.0f;
    else if (M > 3) e[2] = 0.0f;
    if (ll == M - 1) { m = M - 1; return; }
    ll = ll + 1;
  } else {
    ll = 1;
  }
  if (ll == M - 1) {
    float sigmn, sigmx, sinr, cosr, sinl, cosl;
    slasv2_(d[M - 2], e[M - 2], d[M - 1], &sigmn, &sigmx, &sinr, &cosr, &sinl, &cosl);
    d[M - 2] = sigmx; e[M - 2] = 0.0f; d[M - 1] = sigmn;
#pragma unroll
    for (int k = 1; k < 4; k++) {
      float x = vt[M - 2][k], y = vt[M - 1][k];
      vt[M - 2][k] = cosr * x + sinr * y; vt[M - 1][k] = cosr * y - sinr * x;
    }
    m = M - 2;
    return;
  }
  if constexpr (M == 4) {
    if (ll == 2) sv_chase<2, 4>(d, e, vt, thresh, iter, oldll, oldm, idir, smax);
    else sv_chase<1, 4>(d, e, vt, thresh, iter, oldll, oldm, idir, smax);
  } else if constexpr (M == 3) {
    sv_chase<1, 3>(d, e, vt, thresh, iter, oldll, oldm, idir, smax);
  }
}

// Full f32 sgesdd emulation for n=4, returning vec = final VT[:,3].
// Phase-ordered convergence loop (m=4 -> 3 -> 2); per-lane op sequence is
// bit-identical to the mixed loop since m is monotone non-increasing.
__device__ __forceinline__ void gesdd4_vec(const float A0[16], float vec[4]) {
#pragma clang fp contract(off)
  float a[4][4];
#pragma unroll
  for (int i = 0; i < 4; i++)
#pragma unroll
    for (int j = 0; j < 4; j++) a[i][j] = A0[i * 4 + j];
  float d[4], e[3], tauq[4], taup[3];

  // ---- sgebd2 n=4 ----
#pragma unroll
  for (int i = 0; i < 4; i++) {
    float alpha = a[i][i];
    float ss = 0.0f;
#pragma unroll
    for (int r = i + 1; r < 4; r++) ss += a[r][i] * a[r][i];
    if (ss == 0.0f) { tauq[i] = 0.0f; d[i] = alpha; }
    else {
      float xnorm = sqrtf(ss);
      float beta = -sign_f(slapy2f(alpha, xnorm), alpha);
      tauq[i] = (beta - alpha) / beta;
      float scal = 1.0f / (alpha - beta);
#pragma unroll
      for (int r = i + 1; r < 4; r++) a[r][i] *= scal;
      d[i] = beta;
    }
#pragma unroll
    for (int c = i + 1; c < 4; c++) {
      float w = a[i][c];
#pragma unroll
      for (int r = i + 1; r < 4; r++) w += a[r][i] * a[r][c];
      float tw = tauq[i] * w;
      a[i][c] -= tw;
#pragma unroll
      for (int r = i + 1; r < 4; r++) a[r][c] -= tw * a[r][i];
    }
    if (i < 3) {
      float alpha2 = a[i][i + 1];
      float ss2 = 0.0f;
#pragma unroll
      for (int c = i + 2; c < 4; c++) ss2 += a[i][c] * a[i][c];
      if (ss2 == 0.0f) { taup[i] = 0.0f; e[i] = alpha2; }
      else {
        float xnorm = sqrtf(ss2);
        float beta = -sign_f(slapy2f(alpha2, xnorm), alpha2);
        taup[i] = (beta - alpha2) / beta;
        float scal = 1.0f / (alpha2 - beta);
#pragma unroll
        for (int c = i + 2; c < 4; c++) a[i][c] *= scal;
        e[i] = beta;
      }
#pragma unroll
      for (int r = i + 1; r < 4; r++) {
        float w = a[r][i + 1];
#pragma unroll
        for (int c = i + 2; c < 4; c++) w += a[r][c] * a[i][c];
        float tw = taup[i] * w;
        a[r][i + 1] -= tw;
#pragma unroll
        for (int c = i + 2; c < 4; c++) a[r][c] -= tw * a[i][c];
      }
    }
  }

  // ---- VT = I (cols 1..3 tracked) ----
  float vt[4][4];
#pragma unroll
  for (int i = 0; i < 4; i++)
#pragma unroll
    for (int k = 1; k < 4; k++) vt[i][k] = (i == k) ? 1.0f : 0.0f;

  // ---- thresh ----
  float sminoa = fabsf(d[0]);
  if (sminoa != 0.0f) {
    float mu = sminoa;
    bool zr = false;
#pragma unroll
    for (int i = 2; i <= 4; i++) {
      if (!zr) {
        mu = fabsf(d[i - 1]) * (mu / (mu + fabsf(e[i - 2])));
        if (mu < sminoa) sminoa = mu;
        if (sminoa == 0.0f) zr = true;
      }
    }
  }
  sminoa = sminoa / sqrtf(4.0f);
  float thresh = fmaxf(TOL4 * sminoa, 96.0f * UNFL4);
  const int maxit = 96;

  int m = 4, iter = 0, oldll = -1, oldm = -1, idir = 0;
  // phase m==4
  for (int g = 0; g < 300; g++) {
    bool act = (m == 4) && (iter <= maxit);
    if (!__any(act)) break;
    if (act) sv_iter<4>(d, e, vt, thresh, m, iter, oldll, oldm, idir);
  }
  // phase m==3
  for (int g = 0; g < 300; g++) {
    bool act = (m == 3) && (iter <= maxit);
    if (!__any(act)) break;
    if (act) sv_iter<3>(d, e, vt, thresh, m, iter, oldll, oldm, idir);
  }
  // phase m==2
  for (int g = 0; g < 300; g++) {
    bool act = (m == 2) && (iter <= maxit);
    if (!__any(act)) break;
    if (act) sv_iter<2>(d, e, vt, thresh, m, iter, oldll, oldm, idir);
  }

  // ---- make nonnegative ----
#pragma unroll
  for (int i = 0; i < 4; i++) {
    if (d[i] < 0.0f) {
      d[i] = -d[i];
#pragma unroll
      for (int k = 1; k < 4; k++) vt[i][k] = -vt[i][k];
    }
  }
  // ---- sort descending (LAPACK tie rule <=), 3 passes ----
  {
    int isub = 1; float smn = d[0];
    if (d[1] <= smn) { isub = 2; smn = d[1]; }
    if (d[2] <= smn) { isub = 3; smn = d[2]; }
    if (d[3] <= smn) { isub = 4; smn = d[3]; }
    if (isub != 4) {
      if (isub == 1) {
        d[0] = d[3];
#pragma unroll
        for (int k = 1; k < 4; k++) { float t = vt[0][k]; vt[0][k] = vt[3][k]; vt[3][k] = t; }
      } else if (isub == 2) {
        d[1] = d[3];
#pragma unroll
        for (int k = 1; k < 4; k++) { float t = vt[1][k]; vt[1][k] = vt[3][k]; vt[3][k] = t; }
      } else {
        d[2] = d[3];
#pragma unroll
        for (int k = 1; k < 4; k++) { float t = vt[2][k]; vt[2][k] = vt[3][k]; vt[3][k] = t; }
      }
      d[3] = smn;
    }
  }
  {
    int isub = 1; float smn = d[0];
    if (d[1] <= smn) { isub = 2; smn = d[1]; }
    if (d[2] <= smn) { isub = 3; smn = d[2]; }
    if (isub != 3) {
      if (isub == 1) {
        d[0] = d[2];
#pragma unroll
        for (int k = 1; k < 4; k++) { float t = vt[0][k]; vt[0][k] = vt[2][k]; vt[2][k] = t; }
      } else {
        d[1] = d[2];
#pragma unroll
        for (int k = 1; k < 4; k++) { float t = vt[1][k]; vt[1][k] = vt[2][k]; vt[2][k] = t; }
      }
      d[2] = smn;
    }
  }
  {
    int isub = 1; float smn = d[0];
    if (d[1] <= smn) { isub = 2; smn = d[1]; }
    if (isub != 2) {
      d[0] = d[1];
#pragma unroll
      for (int k = 1; k < 4; k++) { float t = vt[0][k]; vt[0][k] = vt[1][k]; vt[1][k] = t; }
      d[1] = smn;
    }
  }

  // ---- sormbr: VT := VT * P^T   (i=2 is a taup=0 no-op; then i=1, i=0) ----
#pragma unroll
  for (int r = 0; r < 4; r++) {
    float w = vt[r][2] + vt[r][3] * a[1][3];
    float tw = taup[1] * w;
    vt[r][2] -= tw;
    vt[r][3] -= tw * a[1][3];
  }
#pragma unroll
  for (int r = 0; r < 4; r++) {
    float w = (vt[r][1] + vt[r][2] * a[0][2]) + vt[r][3] * a[0][3];
    float tw = taup[0] * w;
    vt[r][1] -= tw;
    vt[r][2] -= tw * a[0][2];
    vt[r][3] -= tw * a[0][3];
  }

  vec[0] = vt[0][3]; vec[1] = vt[1][3]; vec[2] = vt[2][3]; vec[3] = vt[3][3];
}

// ---------------- Kernel 1: per-batch pose candidates (1 batch / block) ----

__global__ __launch_bounds__(64) void pose_kernel(const float* __restrict__ Fm,
                                                  const float* __restrict__ Km,
                                                  float* __restrict__ ws) {
  int b = blockIdx.x;
  if (threadIdx.x != 0 || b >= NBATCH) return;
  float* wsR = ws;
  float* wsT = ws + 1152;
  float* wsK = ws + 1536;
  int* scores = (int*)(ws + 1664);
  int* counts = (int*)(ws + 1792);
  for (int c = 0; c < 4; c++) scores[b * 4 + c] = 0;
  counts[b] = 0;
  {
#pragma clang fp contract(off)
    const float* F = Fm + b * 9;
    const float* K = Km + b * 9;
    float E[9];
    for (int i = 0; i < 3; i++) for (int l = 0; l < 3; l++) {
      float acc = 0.0f;
      for (int j = 0; j < 3; j++)
        for (int k = 0; k < 3; k++)
          acc += (K[j * 3 + i] * F[j * 3 + k]) * K[k * 3 + l];
      E[i * 3 + l] = acc;
    }
    float U[3][3], VT[3][3];
    gesdd3_pose(E, U, VT);
    float su = (det3f(U) < 0.0f) ? -1.0f : 1.0f;
    float sv = (det3f(VT) < 0.0f) ? -1.0f : 1.0f;
    for (int i = 0; i < 3; i++) for (int j = 0; j < 3; j++) { U[i][j] *= su; VT[i][j] *= sv; }
    float R1[3][3], R2[3][3];
    for (int r = 0; r < 3; r++) {
      float uw0 = U[r][1], uw1 = -U[r][0], uw2 = U[r][2];
      float vw0 = -U[r][1], vw1 = U[r][0];
      for (int c = 0; c < 3; c++) {
        R1[r][c] = (uw0 * VT[c][0] + uw1 * VT[c][1]) + uw2 * VT[c][2];
        R2[r][c] = (vw0 * VT[c][0] + vw1 * VT[c][1]) + uw2 * VT[c][2];
      }
    }
    float t0 = U[0][2], t1 = U[1][2], t2 = U[2][2];
    for (int c = 0; c < 4; c++) {
      const float (*R)[3] = (c < 2) ? R1 : R2;
      float sg = (c & 1) ? -1.0f : 1.0f;
      float* dst = wsR + (b * 4 + c) * 9;
      for (int i = 0; i < 3; i++) for (int j = 0; j < 3; j++) dst[i * 3 + j] = R[i][j];
      float* dt = wsT + (b * 4 + c) * 3;
      dt[0] = sg * t0; dt[1] = sg * t1; dt[2] = sg * t2;
    }
    const float fx = K[0], fy = K[4], cx = K[2], cy = K[5];
    float invfx = 1.0f / fx, invfy = 1.0f / fy;
    wsK[b * 4 + 0] = invfx;
    wsK[b * 4 + 1] = -(invfx * cx);
    wsK[b * 4 + 2] = invfy;
    wsK[b * 4 + 3] = -(invfy * cy);
  }
}

// ---------------- Kernel 2: per-(point, R-pair) cheirality ----------------
// Round-5 structure (measured 151us): 256-thread blocks, LDS staging of the
// R/t/K tables (block-cooperative coalesced load), LDS histogram.

__global__ __launch_bounds__(256) void score_kernel(const float* __restrict__ pts1,
                                                    const float* __restrict__ pts2,
                                                    const int* __restrict__ bidx,
                                                    float* __restrict__ ws,
                                                    int n_pts) {
  __shared__ float sR[1152];
  __shared__ float sT[384];
  __shared__ float sK[128];
  __shared__ int h01[32], h23[32], hc[32];
  int tid = threadIdx.x;
  for (int i = tid; i < 1152; i += 256) sR[i] = ws[i];
  for (int i = tid; i < 384; i += 256) sT[i] = ws[1152 + i];
  for (int i = tid; i < 128; i += 256) sK[i] = ws[1536 + i];
  if (tid < 32) { h01[tid] = 0; h23[tid] = 0; hc[tid] = 0; }
  __syncthreads();

  int gid = blockIdx.x * 256 + tid;
  int n = gid >> 1, pr = gid & 1;  // pr=0 -> cands {0,1}; pr=1 -> cands {2,3}
  bool active = (n < n_pts);
  bool f0 = false, f1 = false;
  int b = 0;
  if (active) {
    b = bidx[n];
    float x1 = pts1[2 * n], y1 = pts1[2 * n + 1];
    float x2 = pts2[2 * n], y2 = pts2[2 * n + 1];
    float invfx = sK[b * 4 + 0], k02 = sK[b * 4 + 1];
    float invfy = sK[b * 4 + 2], k12 = sK[b * 4 + 3];
    const float* R = sR + (b * 4 + 2 * pr) * 9;
    const float* t = sT + (b * 4 + 2 * pr) * 3;
    float Am[16];
    float row2[4] = { R[6], R[7], R[8], t[2] };
    {
#pragma clang fp contract(off)
      float p1x = invfx * x1 + k02;
      float p1y = invfy * y1 + k12;
      float p2x = invfx * x2 + k02;
      float p2y = invfy * y2 + k12;
      float row0[4] = { R[0], R[1], R[2], t[0] };
      float row1[4] = { R[3], R[4], R[5], t[1] };
      Am[0] = -1.0f; Am[1] = 0.0f; Am[2] = p1x; Am[3] = 0.0f;
      Am[4] = 0.0f; Am[5] = -1.0f; Am[6] = p1y; Am[7] = 0.0f;
#pragma unroll
      for (int k = 0; k < 4; k++) {
        Am[8 + k] = p2x * row2[k] - row0[k];
        Am[12 + k] = p2y * row2[k] - row1[k];
      }
    }
    float vec[4];
    gesdd4_vec(Am, vec);
    {
#pragma clang fp contract(off)
      float v3 = vec[3];
      float X = vec[0] / v3, Y = vec[1] / v3, Z = vec[2] / v3;
      float p0 = row2[0] * X, p1 = row2[1] * Y, p2 = row2[2] * Z;
      float s = (p0 + p1) + p2;
      float t2 = row2[3];
      float z2a = s + t2;        // candidate 2*pr   (+t)
      float z2b = s + (-t2);     // candidate 2*pr+1 (-t)
      bool zpos = (Z > 0.0f);
      f0 = zpos && (z2a > 0.0f);
      f1 = zpos && (z2b > 0.0f);
    }
  }
  if (active) {
    int add = (f0 ? 1 : 0) | (f1 ? (1 << 16) : 0);
    if (add) {
      if (pr == 0) atomicAdd(&h01[b], add);
      else atomicAdd(&h23[b], add);
    }
    if (pr == 0) atomicAdd(&hc[b], 1);
  }
  __syncthreads();
  if (tid < 32) {
    int* scores = (int*)(ws + 1664);
    int* counts = (int*)(ws + 1792);
    int v01 = h01[tid], v23 = h23[tid], vc = hc[tid];
    if (v01 & 0xFFFF) atomicAdd(&scores[tid * 4 + 0], v01 & 0xFFFF);
    if (v01 >> 16) atomicAdd(&scores[tid * 4 + 1], v01 >> 16);
    if (v23 & 0xFFFF) atomicAdd(&scores[tid * 4 + 2], v23 & 0xFFFF);
    if (v23 >> 16) atomicAdd(&scores[tid * 4 + 3], v23 >> 16);
    if (vc) atomicAdd(&counts[tid], vc);
  }
}

// ---------------- Kernel 3: argmax + output ----------------

__global__ __launch_bounds__(64) void final_kernel(const float* __restrict__ ws,
                                                   float* __restrict__ out) {
  int b = threadIdx.x;
  if (b >= NBATCH) return;
  const int* scores = (const int*)(ws + 1664);
  const int* counts = (const int*)(ws + 1792);
  int best = 0, bs = scores[b * 4];
  for (int c = 1; c < 4; c++) {
    int sc = scores[b * 4 + c];
    if (sc > bs) { bs = sc; best = c; }   // np.argmax: first max
  }
  int cnt = counts[b];
  float has = (cnt > 0) ? 1.0f : 0.0f;
  const float* R = ws + (b * 4 + best) * 9;
  const float* t = ws + 1152 + (b * 4 + best) * 3;
  for (int k = 0; k < 9; k++) out[b * 9 + k] = R[k] * has;
  for (int k = 0; k < 3; k++) out[288 + b * 3 + k] = t[k] * has;
  out[384 + b] = (cnt > 0) ? (float)best : 0.0f;
}

// ---------------- Launch ----------------

extern "C" void kernel_launch(void* const* d_in, const int* in_sizes, int n_in,
                              void* d_out, int out_size, void* d_ws, size_t ws_size,
                              hipStream_t stream) {
  (void)n_in; (void)out_size; (void)ws_size;
  const float* F = (const float*)d_in[0];
  const float* K = (const float*)d_in[1];
  const float* p1 = (const float*)d_in[2];
  const float* p2 = (const float*)d_in[3];
  const int* bi = (const int*)d_in[4];
  int n_pts = in_sizes[4];
  float* ws = (float*)d_ws;
  float* out = (float*)d_out;

  pose_kernel<<<NBATCH, 64, 0, stream>>>(F, K, ws);
  int total = n_pts * 2;
  int blocks = (total + 255) / 256;
  score_kernel<<<blocks, 256, 0, stream>>>(p1, p2, bi, ws, n_pts);
  final_kernel<<<1, 64, 0, stream>>>(ws, out);
}

// Round 9
// 190.006 us; speedup vs baseline: 1.3125x; 1.1114x over previous
//
#include <hip/hip_runtime.h>
#include <math.h>

// Problem: B=32 batches, N=262144 points.
// Outputs (f32 flat): best_R [32*9] | best_t [32*3] | best_candidate [32]  (=416)
//
// Reference quirk: vec = Vh[..., :, -1] (last COLUMN of Vh) -> depends on f32
// LAPACK sgesdd sign conventions; we emulate sgesdd bit-faithfully.
// +/-t pairing: A(-t) = A(t)*diag(1,1,1,-1), f32 pipeline exactly sign-
// covariant => vec(-t) = -vec(t) bit-exactly; one SVD serves 2 candidates.
// Round 9: merged-idir chase (sv_chase_m). idir=2 chase == idir=1 chase on the
// reversed window (d,e,vt-rows reversed; VT takes the 2nd Givens pair instead
// of the 1st). Reversal is register renaming (IEEE-exact); halves the per-trip
// divergence union (1 scan + 1 shift + <=2 chase bodies vs 2+2+4).
//
// ws layout (float units):
//   [0,1152)    R_cand[32][4][9]
//   [1152,1536) t_cand[32][4][3]
//   [1536,1664) kinv[32][4]
//   [1664,1792) scores[32][4] (int32)
//   [1792,1824) counts[32]   (int32)

#define NBATCH 32
#define USE_NEW_SLARTG 1   // LAPACK >=3.10 (modern OpenBLAS)

#define EPS4  5.9604645e-08f
#define UNFL4 1.1754944e-38f
#define TOL4  (10.0f * EPS4)

// ---------------- LAPACK-faithful f32 helpers (contract off) ----------------

__device__ __forceinline__ float sign_f(float a, float b) {
  return (b >= 0.0f) ? fabsf(a) : -fabsf(a);
}

__device__ __forceinline__ float slapy2f(float x, float y) {
#pragma clang fp contract(off)
  float xa = fabsf(x), ya = fabsf(y);
  float w = fmaxf(xa, ya), z = fminf(xa, ya);
  if (z == 0.0f) return w;
  float r = z / w;
  return w * sqrtf(1.0f + r * r);
}

__device__ __forceinline__ void slartg_(float f, float g, float* cs, float* sn, float* r) {
#pragma clang fp contract(off)
#if USE_NEW_SLARTG
  if (g == 0.0f) { *cs = 1.0f; *sn = 0.0f; *r = f; return; }
  if (f == 0.0f) { *cs = 0.0f; *sn = (g >= 0.0f) ? 1.0f : -1.0f; *r = fabsf(g); return; }
  float d = sqrtf(f * f + g * g);
  *cs = fabsf(f) / d;
  float rr = (f >= 0.0f) ? d : -d;
  *sn = g / rr;
  *r = rr;
#else
  if (g == 0.0f) { *cs = 1.0f; *sn = 0.0f; *r = f; return; }
  if (f == 0.0f) { *cs = 0.0f; *sn = 1.0f; *r = g; return; }
  float rr = sqrtf(f * f + g * g);
  float c = f / rr, s = g / rr;
  if (fabsf(f) > fabsf(g) && c < 0.0f) { c = -c; s = -s; rr = -rr; }
  *cs = c; *sn = s; *r = rr;
#endif
}

__device__ __forceinline__ void slas2_(float f, float g, float h, float* ssmin, float* ssmax) {
#pragma clang fp contract(off)
  float fa = fabsf(f), ga = fabsf(g), ha = fabsf(h);
  float fhmn = fminf(fa, ha), fhmx = fmaxf(fa, ha);
  if (fhmn == 0.0f) {
    *ssmin = 0.0f;
    if (fhmx == 0.0f) { *ssmax = ga; }
    else {
      float mx = fmaxf(fhmx, ga), mn = fminf(fhmx, ga);
      float r = mn / mx;
      *ssmax = mx * sqrtf(1.0f + r * r);
    }
  } else {
    if (ga < fhmx) {
      float as_ = 1.0f + fhmn / fhmx;
      float at = (fhmx - fhmn) / fhmx;
      float au = ga / fhmx; au = au * au;
      float c = 2.0f / (sqrtf(as_ * as_ + au) + sqrtf(at * at + au));
      *ssmin = fhmn * c;
      *ssmax = fhmx / c;
    } else {
      float au = fhmx / ga;
      if (au == 0.0f) { *ssmin = (fhmn * fhmx) / ga; *ssmax = ga; }
      else {
        float as_ = 1.0f + fhmn / fhmx;
        float at = (fhmx - fhmn) / fhmx;
        float aas = as_ * au, aat = at * au;
        float c = 1.0f / (sqrtf(1.0f + aas * aas) + sqrtf(1.0f + aat * aat));
        float sm = (fhmn * c) * au;
        *ssmin = sm + sm;
        *ssmax = ga / (c + c);
      }
    }
  }
}

__device__ __forceinline__ void slasv2_(float f, float g, float h, float* ssmin, float* ssmax,
                        float* snr, float* csr, float* snl, float* csl) {
#pragma clang fp contract(off)
  const float EPS = EPS4;
  float ft = f, fa = fabsf(f), ht = h, ha = fabsf(h);
  int pmax = 1;
  bool swap_ = (ha > fa);
  if (swap_) {
    pmax = 3;
    float t = ft; ft = ht; ht = t;
    t = fa; fa = ha; ha = t;
  }
  float gt = g, ga = fabsf(g);
  float clt = 0.f, crt = 0.f, slt = 0.f, srt = 0.f;
  if (ga == 0.0f) {
    *ssmin = ha; *ssmax = fa;
    clt = 1.0f; crt = 1.0f; slt = 0.0f; srt = 0.0f;
  } else {
    bool gasmal = true;
    if (ga > fa) {
      pmax = 2;
      if ((fa / ga) < EPS) {
        gasmal = false;
        *ssmax = ga;
        if (ha > 1.0f) *ssmin = fa / (ga / ha);
        else *ssmin = (fa / ga) * ha;
        clt = 1.0f; slt = ht / gt; srt = 1.0f; crt = ft / gt;
      }
    }
    if (gasmal) {
      float dd = fa - ha;
      float l;
      if (dd == fa) l = 1.0f; else l = dd / fa;
      float mm_ = gt / ft;
      float t = 2.0f - l;
      float mm = mm_ * mm_, tt = t * t;
      float s = sqrtf(tt + mm);
      float r;
      if (l == 0.0f) r = fabsf(mm_); else r = sqrtf(l * l + mm);
      float a = 0.5f * (s + r);
      *ssmin = ha / a;
      *ssmax = fa * a;
      if (mm == 0.0f) {
        if (l == 0.0f) t = sign_f(2.0f, ft) * sign_f(1.0f, gt);
        else t = gt / sign_f(dd, ft) + mm_ / t;
      } else {
        t = (mm_ / (s + t) + mm_ / (r + l)) * (1.0f + a);
      }
      float l2 = sqrtf(t * t + 4.0f);
      crt = 2.0f / l2;
      srt = t / l2;
      clt = (crt + srt * mm_) / a;
      slt = (ht / ft) * srt / a;
    }
  }
  if (swap_) { *csl = srt; *snl = crt; *csr = slt; *snr = clt; }
  else { *csl = clt; *snl = slt; *csr = crt; *snr = srt; }
  float tsign = 1.0f;
  if (pmax == 1) tsign = sign_f(1.0f, *csr) * sign_f(1.0f, *csl) * sign_f(1.0f, f);
  if (pmax == 2) tsign = sign_f(1.0f, *snr) * sign_f(1.0f, *csl) * sign_f(1.0f, g);
  if (pmax == 3) tsign = sign_f(1.0f, *snr) * sign_f(1.0f, *snl) * sign_f(1.0f, h);
  *ssmax = sign_f(*ssmax, tsign);
  *ssmin = sign_f(*ssmin, tsign * sign_f(1.0f, f) * sign_f(1.0f, h));
}

// =============== static (register-resident) n=3 sbdsqr with U+VT (pose) =====
// (unchanged from round 8 — perf-irrelevant, 32 threads total)

__device__ __forceinline__ void sv3_chase(float (&d)[3], float (&e)[2],
                                          float (&vt)[3][3], float (&u)[3][3],
                                          float thresh, int& iter, int& oldll,
                                          int& oldm, int& idir, float smax) {
#pragma clang fp contract(off)
  if (1 > oldm || 3 < oldll)
    idir = (fabsf(d[0]) >= fabsf(d[2])) ? 1 : 2;

  bool deflated = false;
  float sminl = 0.0f;
  if (idir == 1) {
    if (fabsf(e[1]) <= TOL4 * fabsf(d[2])) { e[1] = 0.0f; return; }
    float mu = fabsf(d[0]); sminl = mu;
    if (fabsf(e[0]) <= TOL4 * mu) { e[0] = 0.0f; deflated = true; }
    else {
      mu = fabsf(d[1]) * (mu / (mu + fabsf(e[0])));
      if (mu < sminl) sminl = mu;
      if (fabsf(e[1]) <= TOL4 * mu) { e[1] = 0.0f; deflated = true; }
      else {
        mu = fabsf(d[2]) * (mu / (mu + fabsf(e[1])));
        if (mu < sminl) sminl = mu;
      }
    }
  } else {
    if (fabsf(e[0]) <= TOL4 * fabsf(d[0])) { e[0] = 0.0f; return; }
    float mu = fabsf(d[2]); sminl = mu;
    if (fabsf(e[1]) <= TOL4 * mu) { e[1] = 0.0f; deflated = true; }
    else {
      mu = fabsf(d[1]) * (mu / (mu + fabsf(e[1])));
      if (mu < sminl) sminl = mu;
      if (fabsf(e[0]) <= TOL4 * mu) { e[0] = 0.0f; deflated = true; }
      else {
        mu = fabsf(d[0]) * (mu / (mu + fabsf(e[0])));
        if (mu < sminl) sminl = mu;
      }
    }
  }
  if (deflated) return;
  oldll = 1; oldm = 3;

  float shift = 0.0f, rdum;
  if (!(3.0f * TOL4 * (sminl / smax) <= fmaxf(EPS4, 0.01f * TOL4))) {
    float sll;
    if (idir == 1) { sll = fabsf(d[0]); slas2_(d[1], e[1], d[2], &shift, &rdum); }
    else { sll = fabsf(d[2]); slas2_(d[0], e[0], d[1], &shift, &rdum); }
    if (sll > 0.0f) {
      float q = shift / sll;
      if (q * q < EPS4) shift = 0.0f;
    }
  }
  iter += 2;

  if (shift == 0.0f) {
    if (idir == 1) {
      float cs = 1.0f, oldcs = 1.0f, sn = 0.0f, oldsn = 0.0f, r = 0.0f;
      float c1, s1, c2, s2, rr;
      slartg_(d[0] * cs, e[0], &c1, &s1, &r); cs = c1; sn = s1;
      slartg_(oldcs * r, d[1] * sn, &c2, &s2, &rr); oldcs = c2; oldsn = s2;
      d[0] = rr;
#pragma unroll
      for (int k = 0; k < 3; k++) {
        float x = vt[0][k], y = vt[1][k];
        vt[0][k] = cs * x + sn * y; vt[1][k] = cs * y - sn * x;
      }
#pragma unroll
      for (int k = 0; k < 3; k++) {
        float x = u[k][0], y = u[k][1];
        u[k][0] = oldcs * x + oldsn * y; u[k][1] = oldcs * y - oldsn * x;
      }
      slartg_(d[1] * cs, e[1], &c1, &s1, &r); cs = c1; sn = s1;
      e[0] = oldsn * r;
      slartg_(oldcs * r, d[2] * sn, &c2, &s2, &rr); oldcs = c2; oldsn = s2;
      d[1] = rr;
#pragma unroll
      for (int k = 0; k < 3; k++) {
        float x = vt[1][k], y = vt[2][k];
        vt[1][k] = cs * x + sn * y; vt[2][k] = cs * y - sn * x;
      }
#pragma unroll
      for (int k = 0; k < 3; k++) {
        float x = u[k][1], y = u[k][2];
        u[k][1] = oldcs * x + oldsn * y; u[k][2] = oldcs * y - oldsn * x;
      }
      float h = d[2] * cs;
      d[2] = h * oldcs;
      e[1] = h * oldsn;
      if (fabsf(e[1]) <= thresh) e[1] = 0.0f;
    } else {
      float cs = 1.0f, oldcs = 1.0f, sn = 0.0f, oldsn = 0.0f, r = 0.0f;
      float c1, s1, c2, s2, rr;
      slartg_(d[2] * cs, e[1], &c1, &s1, &r); cs = c1; sn = s1;
      slartg_(oldcs * r, d[1] * sn, &c2, &s2, &rr); oldcs = c2; oldsn = s2;
      d[2] = rr;
#pragma unroll
      for (int k = 0; k < 3; k++) {
        float x = u[k][2], y = u[k][1];
        u[k][2] = cs * x + sn * y; u[k][1] = cs * y - sn * x;
      }
#pragma unroll
      for (int k = 0; k < 3; k++) {
        float x = vt[2][k], y = vt[1][k];
        vt[2][k] = oldcs * x + oldsn * y; vt[1][k] = oldcs * y - oldsn * x;
      }
      slartg_(d[1] * cs, e[0], &c1, &s1, &r); cs = c1; sn = s1;
      e[1] = oldsn * r;
      slartg_(oldcs * r, d[0] * sn, &c2, &s2, &rr); oldcs = c2; oldsn = s2;
      d[1] = rr;
#pragma unroll
      for (int k = 0; k < 3; k++) {
        float x = u[k][1], y = u[k][0];
        u[k][1] = cs * x + sn * y; u[k][0] = cs * y - sn * x;
      }
#pragma unroll
      for (int k = 0; k < 3; k++) {
        float x = vt[1][k], y = vt[0][k];
        vt[1][k] = oldcs * x + oldsn * y; vt[0][k] = oldcs * y - oldsn * x;
      }
      float h = d[0] * cs;
      d[0] = h * oldcs;
      e[0] = h * oldsn;
      if (fabsf(e[0]) <= thresh) e[0] = 0.0f;
    }
  } else {
    if (idir == 1) {
      float f = (fabsf(d[0]) - shift) * (sign_f(1.0f, d[0]) + shift / d[0]);
      float g = e[0];
      float cosr, sinr, cosl, sinl, r, rr;
      slartg_(f, g, &cosr, &sinr, &r);
      f = cosr * d[0] + sinr * e[0];
      e[0] = cosr * e[0] - sinr * d[0];
      g = sinr * d[1];
      d[1] = cosr * d[1];
      slartg_(f, g, &cosl, &sinl, &rr);
      d[0] = rr;
      f = cosl * e[0] + sinl * d[1];
      d[1] = cosl * d[1] - sinl * e[0];
      g = sinl * e[1];
      e[1] = cosl * e[1];
#pragma unroll
      for (int k = 0; k < 3; k++) {
        float x = vt[0][k], y = vt[1][k];
        vt[0][k] = cosr * x + sinr * y; vt[1][k] = cosr * y - sinr * x;
      }
#pragma unroll
      for (int k = 0; k < 3; k++) {
        float x = u[k][0], y = u[k][1];
        u[k][0] = cosl * x + sinl * y; u[k][1] = cosl * y - sinl * x;
      }
      slartg_(f, g, &cosr, &sinr, &r);
      e[0] = r;
      f = cosr * d[1] + sinr * e[1];
      e[1] = cosr * e[1] - sinr * d[1];
      g = sinr * d[2];
      d[2] = cosr * d[2];
      slartg_(f, g, &cosl, &sinl, &rr);
      d[1] = rr;
      f = cosl * e[1] + sinl * d[2];
      d[2] = cosl * d[2] - sinl * e[1];
#pragma unroll
      for (int k = 0; k < 3; k++) {
        float x = vt[1][k], y = vt[2][k];
        vt[1][k] = cosr * x + sinr * y; vt[2][k] = cosr * y - sinr * x;
      }
#pragma unroll
      for (int k = 0; k < 3; k++) {
        float x = u[k][1], y = u[k][2];
        u[k][1] = cosl * x + sinl * y; u[k][2] = cosl * y - sinl * x;
      }
      e[1] = f;
      if (fabsf(e[1]) <= thresh) e[1] = 0.0f;
    } else {
      float f = (fabsf(d[2]) - shift) * (sign_f(1.0f, d[2]) + shift / d[2]);
      float g = e[1];
      float cosr, sinr, cosl, sinl, r, rr;
      slartg_(f, g, &cosr, &sinr, &r);
      f = cosr * d[2] + sinr * e[1];
      e[1] = cosr * e[1] - sinr * d[2];
      g = sinr * d[1];
      d[1] = cosr * d[1];
      slartg_(f, g, &cosl, &sinl, &rr);
      d[2] = rr;
      f = cosl * e[1] + sinl * d[1];
      d[1] = cosl * d[1] - sinl * e[1];
      g = sinl * e[0];
      e[0] = cosl * e[0];
#pragma unroll
      for (int k = 0; k < 3; k++) {
        float x = u[k][2], y = u[k][1];
        u[k][2] = cosr * x + sinr * y; u[k][1] = cosr * y - sinr * x;
      }
#pragma unroll
      for (int k = 0; k < 3; k++) {
        float x = vt[2][k], y = vt[1][k];
        vt[2][k] = cosl * x + sinl * y; vt[1][k] = cosl * y - sinl * x;
      }
      slartg_(f, g, &cosr, &sinr, &r);
      e[1] = r;
      f = cosr * d[1] + sinr * e[0];
      e[0] = cosr * e[0] - sinr * d[1];
      g = sinr * d[0];
      d[0] = cosr * d[0];
      slartg_(f, g, &cosl, &sinl, &rr);
      d[1] = rr;
      f = cosl * e[0] + sinl * d[0];
      d[0] = cosl * d[0] - sinl * e[0];
#pragma unroll
      for (int k = 0; k < 3; k++) {
        float x = u[k][1], y = u[k][0];
        u[k][1] = cosr * x + sinr * y; u[k][0] = cosr * y - sinr * x;
      }
#pragma unroll
      for (int k = 0; k < 3; k++) {
        float x = vt[1][k], y = vt[0][k];
        vt[1][k] = cosl * x + sinl * y; vt[0][k] = cosl * y - sinl * x;
      }
      e[0] = f;
      if (fabsf(e[0]) <= thresh) e[0] = 0.0f;
    }
  }
}

__device__ __forceinline__ void sv3_iter3(float (&d)[3], float (&e)[2],
                                          float (&vt)[3][3], float (&u)[3][3],
                                          float thresh, int& m, int& iter,
                                          int& oldll, int& oldm, int& idir) {
#pragma clang fp contract(off)
  float smax = fabsf(d[2]);
  int ll = 0;
  bool split = false;
  if (fabsf(e[1]) <= thresh) { split = true; ll = 2; }
  else {
    smax = fmaxf(smax, fmaxf(fabsf(d[1]), fabsf(e[1])));
    if (fabsf(e[0]) <= thresh) { split = true; ll = 1; }
    else {
      smax = fmaxf(smax, fmaxf(fabsf(d[0]), fabsf(e[0])));
      ll = 1;
    }
  }
  if (split) {
    if (ll == 2) { e[1] = 0.0f; m = 2; return; }
    e[0] = 0.0f;
    float sigmn, sigmx, sinr, cosr, sinl, cosl;
    slasv2_(d[1], e[1], d[2], &sigmn, &sigmx, &sinr, &cosr, &sinl, &cosl);
    d[1] = sigmx; e[1] = 0.0f; d[2] = sigmn;
#pragma unroll
    for (int k = 0; k < 3; k++) {
      float x = vt[1][k], y = vt[2][k];
      vt[1][k] = cosr * x + sinr * y; vt[2][k] = cosr * y - sinr * x;
    }
#pragma unroll
    for (int k = 0; k < 3; k++) {
      float x = u[k][1], y = u[k][2];
      u[k][1] = cosl * x + sinl * y; u[k][2] = cosl * y - sinl * x;
    }
    m = 1;
    return;
  }
  sv3_chase(d, e, vt, u, thresh, iter, oldll, oldm, idir, smax);
}

__device__ __forceinline__ void sv3_iter2(float (&d)[3], float (&e)[2],
                                          float (&vt)[3][3], float (&u)[3][3],
                                          float thresh, int& m) {
#pragma clang fp contract(off)
  if (fabsf(e[0]) <= thresh) { e[0] = 0.0f; m = 1; return; }
  float sigmn, sigmx, sinr, cosr, sinl, cosl;
  slasv2_(d[0], e[0], d[1], &sigmn, &sigmx, &sinr, &cosr, &sinl, &cosl);
  d[0] = sigmx; e[0] = 0.0f; d[1] = sigmn;
#pragma unroll
  for (int k = 0; k < 3; k++) {
    float x = vt[0][k], y = vt[1][k];
    vt[0][k] = cosr * x + sinr * y; vt[1][k] = cosr * y - sinr * x;
  }
#pragma unroll
  for (int k = 0; k < 3; k++) {
    float x = u[k][0], y = u[k][1];
    u[k][0] = cosl * x + sinl * y; u[k][1] = cosl * y - sinl * x;
  }
  m = 0;
}

// Full f32 sgesdd emulation for n=3 (jobz='A'): sgebd2 -> static sbdsqr -> Q/P.
__device__ void gesdd3_pose(const float E[9], float (&u)[3][3], float (&vt)[3][3]) {
#pragma clang fp contract(off)
  float a[3][3];
#pragma unroll
  for (int i = 0; i < 3; i++)
#pragma unroll
    for (int j = 0; j < 3; j++) a[i][j] = E[i * 3 + j];
  float d[3], e[2], tauq[3], taup[2];

  {
    float alpha = a[0][0];
    float ss = a[1][0] * a[1][0] + a[2][0] * a[2][0];
    if (ss == 0.0f) { tauq[0] = 0.0f; d[0] = alpha; }
    else {
      float xnorm = sqrtf(ss);
      float beta = -sign_f(slapy2f(alpha, xnorm), alpha);
      tauq[0] = (beta - alpha) / beta;
      float scal = 1.0f / (alpha - beta);
      a[1][0] *= scal; a[2][0] *= scal;
      d[0] = beta;
    }
#pragma unroll
    for (int c = 1; c < 3; c++) {
      float w = (a[0][c] + a[1][0] * a[1][c]) + a[2][0] * a[2][c];
      float tw = tauq[0] * w;
      a[0][c] -= tw; a[1][c] -= tw * a[1][0]; a[2][c] -= tw * a[2][0];
    }
    float alpha2 = a[0][1];
    float ss2 = a[0][2] * a[0][2];
    if (ss2 == 0.0f) { taup[0] = 0.0f; e[0] = alpha2; }
    else {
      float xnorm = sqrtf(ss2);
      float beta = -sign_f(slapy2f(alpha2, xnorm), alpha2);
      taup[0] = (beta - alpha2) / beta;
      float scal = 1.0f / (alpha2 - beta);
      a[0][2] *= scal;
      e[0] = beta;
    }
#pragma unroll
    for (int r = 1; r < 3; r++) {
      float w = a[r][1] + a[r][2] * a[0][2];
      float tw = taup[0] * w;
      a[r][1] -= tw; a[r][2] -= tw * a[0][2];
    }
  }
  {
    float alpha = a[1][1];
    float ss = a[2][1] * a[2][1];
    if (ss == 0.0f) { tauq[1] = 0.0f; d[1] = alpha; }
    else {
      float xnorm = sqrtf(ss);
      float beta = -sign_f(slapy2f(alpha, xnorm), alpha);
      tauq[1] = (beta - alpha) / beta;
      float scal = 1.0f / (alpha - beta);
      a[2][1] *= scal;
      d[1] = beta;
    }
    {
      float w = a[1][2] + a[2][1] * a[2][2];
      float tw = tauq[1] * w;
      a[1][2] -= tw; a[2][2] -= tw * a[2][1];
    }
    taup[1] = 0.0f; e[1] = a[1][2];
    {
      float w = a[2][2];
      float tw = taup[1] * w;
      a[2][2] -= tw;
    }
  }
  tauq[2] = 0.0f;
  d[2] = a[2][2];

#pragma unroll
  for (int i = 0; i < 3; i++)
#pragma unroll
    for (int j = 0; j < 3; j++) {
      vt[i][j] = (i == j) ? 1.0f : 0.0f;
      u[i][j] = (i == j) ? 1.0f : 0.0f;
    }

  {
    float sminoa = fabsf(d[0]);
    if (sminoa != 0.0f) {
      float mu = sminoa;
      mu = fabsf(d[1]) * (mu / (mu + fabsf(e[0])));
      if (mu < sminoa) sminoa = mu;
      if (sminoa != 0.0f) {
        mu = fabsf(d[2]) * (mu / (mu + fabsf(e[1])));
        if (mu < sminoa) sminoa = mu;
      }
    }
    sminoa = sminoa / sqrtf(3.0f);
    float thresh = fmaxf(TOL4 * sminoa, 54.0f * UNFL4);
    int m = 3, iter = 0, oldll = -1, oldm = -1, idir = 0, guard = 0;
    while (guard++ < 500) {
      if (m <= 1 || iter > 54) break;
      if (m == 3) sv3_iter3(d, e, vt, u, thresh, m, iter, oldll, oldm, idir);
      else sv3_iter2(d, e, vt, u, thresh, m);
    }
  }

#pragma unroll
  for (int i = 0; i < 3; i++) {
    if (d[i] < 0.0f) {
      d[i] = -d[i];
#pragma unroll
      for (int k = 0; k < 3; k++) vt[i][k] = -vt[i][k];
    }
  }
  {
    int isub = 1; float smn = d[0];
    if (d[1] <= smn) { isub = 2; smn = d[1]; }
    if (d[2] <= smn) { isub = 3; smn = d[2]; }
    if (isub != 3) {
      if (isub == 1) {
        d[0] = d[2];
#pragma unroll
        for (int k = 0; k < 3; k++) { float t = vt[0][k]; vt[0][k] = vt[2][k]; vt[2][k] = t; }
#pragma unroll
        for (int k = 0; k < 3; k++) { float t = u[k][0]; u[k][0] = u[k][2]; u[k][2] = t; }
      } else {
        d[1] = d[2];
#pragma unroll
        for (int k = 0; k < 3; k++) { float t = vt[1][k]; vt[1][k] = vt[2][k]; vt[2][k] = t; }
#pragma unroll
        for (int k = 0; k < 3; k++) { float t = u[k][1]; u[k][1] = u[k][2]; u[k][2] = t; }
      }
      d[2] = smn;
    }
  }
  {
    int isub = 1; float smn = d[0];
    if (d[1] <= smn) { isub = 2; smn = d[1]; }
    if (isub != 2) {
      d[0] = d[1]; d[1] = smn;
#pragma unroll
      for (int k = 0; k < 3; k++) { float t = vt[0][k]; vt[0][k] = vt[1][k]; vt[1][k] = t; }
#pragma unroll
      for (int k = 0; k < 3; k++) { float t = u[k][0]; u[k][0] = u[k][1]; u[k][1] = t; }
    }
  }

#pragma unroll
  for (int c = 0; c < 3; c++) {
    float w = u[2][c];
    float tw = tauq[2] * w;
    u[2][c] -= tw;
  }
#pragma unroll
  for (int c = 0; c < 3; c++) {
    float w = u[1][c] + a[2][1] * u[2][c];
    float tw = tauq[1] * w;
    u[1][c] -= tw; u[2][c] -= tw * a[2][1];
  }
#pragma unroll
  for (int c = 0; c < 3; c++) {
    float w = (u[0][c] + a[1][0] * u[1][c]) + a[2][0] * u[2][c];
    float tw = tauq[0] * w;
    u[0][c] -= tw; u[1][c] -= tw * a[1][0]; u[2][c] -= tw * a[2][0];
  }
#pragma unroll
  for (int r = 0; r < 3; r++) {
    float w = vt[r][2];
    float tw = taup[1] * w;
    vt[r][2] -= tw;
  }
#pragma unroll
  for (int r = 0; r < 3; r++) {
    float w = vt[r][1] + vt[r][2] * a[0][2];
    float tw = taup[0] * w;
    vt[r][1] -= tw; vt[r][2] -= tw * a[0][2];
  }
}

__device__ __forceinline__ float det3f(const float M[3][3]) {
#pragma clang fp contract(off)
  return M[0][0] * (M[1][1] * M[2][2] - M[1][2] * M[2][1])
       - M[0][1] * (M[1][0] * M[2][2] - M[1][2] * M[2][0])
       + M[0][2] * (M[1][0] * M[2][1] - M[1][1] * M[2][0]);
}

// =============== static n=4 sgesdd, VT cols 1..3, MERGED-idir chase =========
// idir=2 == idir=1 on the reversed window (d,e,vt-rows reversed = B^T frame).
// Transposition swaps left/right rotations, so VT takes the 1st Givens pair
// when idir==1 and the 2nd pair when idir==2 (per-element select). Reversal is
// register renaming -> bit-exact. slas2 is symmetric in (f,h) (uses |f|,|h|
// via min/max only), so the shift call is shared too.

template <int LL, int M>
__device__ __forceinline__ void sv_rev(float (&d)[4], float (&e)[3], float (&vt)[4][4]) {
#pragma unroll
  for (int k = 0; k < (M - LL + 1) / 2; k++) {
    float t = d[LL - 1 + k]; d[LL - 1 + k] = d[M - 1 - k]; d[M - 1 - k] = t;
  }
#pragma unroll
  for (int k = 0; k < (M - LL) / 2; k++) {
    float t = e[LL - 1 + k]; e[LL - 1 + k] = e[M - 2 - k]; e[M - 2 - k] = t;
  }
#pragma unroll
  for (int k = 0; k < (M - LL + 1) / 2; k++)
#pragma unroll
    for (int c = 1; c < 4; c++) {
      float t = vt[LL - 1 + k][c]; vt[LL - 1 + k][c] = vt[M - 1 - k][c]; vt[M - 1 - k][c] = t;
    }
}

template <int LL, int M>
__device__ __forceinline__ void sv_chase_m(float (&d)[4], float (&e)[3], float (&vt)[4][4],
                                           float thresh, int& iter, int& oldll, int& oldm,
                                           int& idir, float smax) {
#pragma clang fp contract(off)
  if (LL > oldm || M < oldll)
    idir = (fabsf(d[LL - 1]) >= fabsf(d[M - 1])) ? 1 : 2;
  const bool rev = (idir == 2);

  if (rev) sv_rev<LL, M>(d, e, vt);

  bool done = false;
  // convergence test (idir=1 form on possibly-reversed window)
  if (fabsf(e[M - 2]) <= TOL4 * fabsf(d[M - 1])) { e[M - 2] = 0.0f; done = true; }

  float sminl = 0.0f;
  if (!done) {
    float mu = fabsf(d[LL - 1]); sminl = mu;
    bool defl = false;
#pragma unroll
    for (int lll = LL; lll <= M - 1; lll++) {
      if (!defl) {
        if (fabsf(e[lll - 1]) <= TOL4 * mu) { e[lll - 1] = 0.0f; defl = true; }
        else {
          mu = fabsf(d[lll]) * (mu / (mu + fabsf(e[lll - 1])));
          if (mu < sminl) sminl = mu;
        }
      }
    }
    if (defl) done = true;
  }

  if (!done) {
    oldll = LL; oldm = M;

    float shift = 0.0f, rdum;
    if (!(4.0f * TOL4 * (sminl / smax) <= fmaxf(EPS4, 0.01f * TOL4))) {
      float sll = fabsf(d[LL - 1]);
      slas2_(d[M - 2], e[M - 2], d[M - 1], &shift, &rdum);
      if (sll > 0.0f) {
        float q = shift / sll;
        if (q * q < EPS4) shift = 0.0f;
      }
    }
    iter += M - LL;

    if (shift == 0.0f) {
      float cs = 1.0f, oldcs = 1.0f, sn = 0.0f, oldsn = 0.0f, r = 0.0f;
#pragma unroll
      for (int i = LL; i <= M - 1; i++) {
        float c1, s1;
        slartg_(d[i - 1] * cs, e[i - 1], &c1, &s1, &r);
        cs = c1; sn = s1;
        if (i > LL) e[i - 2] = oldsn * r;
        float c2, s2, rr;
        slartg_(oldcs * r, d[i] * sn, &c2, &s2, &rr);
        oldcs = c2; oldsn = s2;
        d[i - 1] = rr;
        float cu = rev ? oldcs : cs;
        float su = rev ? oldsn : sn;
#pragma unroll
        for (int k = 1; k < 4; k++) {
          float x = vt[i - 1][k], y = vt[i][k];
          vt[i - 1][k] = cu * x + su * y; vt[i][k] = cu * y - su * x;
        }
      }
      float h = d[M - 1] * cs;
      d[M - 1] = h * oldcs;
      e[M - 2] = h * oldsn;
      if (fabsf(e[M - 2]) <= thresh) e[M - 2] = 0.0f;
    } else {
      float f = (fabsf(d[LL - 1]) - shift) * (sign_f(1.0f, d[LL - 1]) + shift / d[LL - 1]);
      float g = e[LL - 1];
#pragma unroll
      for (int i = LL; i <= M - 1; i++) {
        float cosr, sinr, r;
        slartg_(f, g, &cosr, &sinr, &r);
        if (i > LL) e[i - 2] = r;
        f = cosr * d[i - 1] + sinr * e[i - 1];
        e[i - 1] = cosr * e[i - 1] - sinr * d[i - 1];
        g = sinr * d[i];
        d[i] = cosr * d[i];
        float cosl, sinl, rr;
        slartg_(f, g, &cosl, &sinl, &rr);
        d[i - 1] = rr;
        f = cosl * e[i - 1] + sinl * d[i];
        d[i] = cosl * d[i] - sinl * e[i - 1];
        if (i < M - 1) {
          g = sinl * e[i];
          e[i] = cosl * e[i];
        }
        float cu = rev ? cosl : cosr;
        float su = rev ? sinl : sinr;
#pragma unroll
        for (int k = 1; k < 4; k++) {
          float x = vt[i - 1][k], y = vt[i][k];
          vt[i - 1][k] = cu * x + su * y; vt[i][k] = cu * y - su * x;
        }
      }
      e[M - 2] = f;
      if (fabsf(e[M - 2]) <= thresh) e[M - 2] = 0.0f;
    }
  }

  if (rev) sv_rev<LL, M>(d, e, vt);
}

template <int M>
__device__ __forceinline__ void sv_iter(float (&d)[4], float (&e)[3], float (&vt)[4][4],
                                        float thresh, int& m, int& iter,
                                        int& oldll, int& oldm, int& idir) {
#pragma clang fp contract(off)
  float smax = fabsf(d[M - 1]);
  float smin = smax;
  int ll = 0;
  bool split = false;
#pragma unroll
  for (int lll = 1; lll <= M - 1; lll++) {
    if (!split) {
      const int llc = M - lll;
      float abss = fabsf(d[llc - 1]);
      float abse = fabsf(e[llc - 1]);
      if (abse <= thresh) { split = true; ll = llc; }
      else {
        if (abss < smin) smin = abss;
        float mx = fmaxf(abss, abse);
        if (mx > smax) smax = mx;
        ll = llc;
      }
    }
  }
  (void)smin;
  if (split) {
    if (ll == 1) e[0] = 0.0f;
    else if (M > 2 && ll == 2) e[1] = 0.0f;
    else if (M > 3) e[2] = 0.0f;
    if (ll == M - 1) { m = M - 1; return; }
    ll = ll + 1;
  } else {
    ll = 1;
  }
  if (ll == M - 1) {
    float sigmn, sigmx, sinr, cosr, sinl, cosl;
    slasv2_(d[M - 2], e[M - 2], d[M - 1], &sigmn, &sigmx, &sinr, &cosr, &sinl, &cosl);
    d[M - 2] = sigmx; e[M - 2] = 0.0f; d[M - 1] = sigmn;
#pragma unroll
    for (int k = 1; k < 4; k++) {
      float x = vt[M - 2][k], y = vt[M - 1][k];
      vt[M - 2][k] = cosr * x + sinr * y; vt[M - 1][k] = cosr * y - sinr * x;
    }
    m = M - 2;
    return;
  }
  if constexpr (M == 4) {
    if (ll == 2) sv_chase_m<2, 4>(d, e, vt, thresh, iter, oldll, oldm, idir, smax);
    else sv_chase_m<1, 4>(d, e, vt, thresh, iter, oldll, oldm, idir, smax);
  } else if constexpr (M == 3) {
    sv_chase_m<1, 3>(d, e, vt, thresh, iter, oldll, oldm, idir, smax);
  }
}

// Full f32 sgesdd emulation for n=4, returning vec = final VT[:,3].
// Phase-ordered convergence loop (m=4 -> 3 -> 2); per-lane op sequence is
// bit-identical to the mixed loop since m is monotone non-increasing.
__device__ __forceinline__ void gesdd4_vec(const float A0[16], float vec[4]) {
#pragma clang fp contract(off)
  float a[4][4];
#pragma unroll
  for (int i = 0; i < 4; i++)
#pragma unroll
    for (int j = 0; j < 4; j++) a[i][j] = A0[i * 4 + j];
  float d[4], e[3], tauq[4], taup[3];

  // ---- sgebd2 n=4 ----
#pragma unroll
  for (int i = 0; i < 4; i++) {
    float alpha = a[i][i];
    float ss = 0.0f;
#pragma unroll
    for (int r = i + 1; r < 4; r++) ss += a[r][i] * a[r][i];
    if (ss == 0.0f) { tauq[i] = 0.0f; d[i] = alpha; }
    else {
      float xnorm = sqrtf(ss);
      float beta = -sign_f(slapy2f(alpha, xnorm), alpha);
      tauq[i] = (beta - alpha) / beta;
      float scal = 1.0f / (alpha - beta);
#pragma unroll
      for (int r = i + 1; r < 4; r++) a[r][i] *= scal;
      d[i] = beta;
    }
#pragma unroll
    for (int c = i + 1; c < 4; c++) {
      float w = a[i][c];
#pragma unroll
      for (int r = i + 1; r < 4; r++) w += a[r][i] * a[r][c];
      float tw = tauq[i] * w;
      a[i][c] -= tw;
#pragma unroll
      for (int r = i + 1; r < 4; r++) a[r][c] -= tw * a[r][i];
    }
    if (i < 3) {
      float alpha2 = a[i][i + 1];
      float ss2 = 0.0f;
#pragma unroll
      for (int c = i + 2; c < 4; c++) ss2 += a[i][c] * a[i][c];
      if (ss2 == 0.0f) { taup[i] = 0.0f; e[i] = alpha2; }
      else {
        float xnorm = sqrtf(ss2);
        float beta = -sign_f(slapy2f(alpha2, xnorm), alpha2);
        taup[i] = (beta - alpha2) / beta;
        float scal = 1.0f / (alpha2 - beta);
#pragma unroll
        for (int c = i + 2; c < 4; c++) a[i][c] *= scal;
        e[i] = beta;
      }
#pragma unroll
      for (int r = i + 1; r < 4; r++) {
        float w = a[r][i + 1];
#pragma unroll
        for (int c = i + 2; c < 4; c++) w += a[r][c] * a[i][c];
        float tw = taup[i] * w;
        a[r][i + 1] -= tw;
#pragma unroll
        for (int c = i + 2; c < 4; c++) a[r][c] -= tw * a[i][c];
      }
    }
  }

  // ---- VT = I (cols 1..3 tracked) ----
  float vt[4][4];
#pragma unroll
  for (int i = 0; i < 4; i++)
#pragma unroll
    for (int k = 1; k < 4; k++) vt[i][k] = (i == k) ? 1.0f : 0.0f;

  // ---- thresh ----
  float sminoa = fabsf(d[0]);
  if (sminoa != 0.0f) {
    float mu = sminoa;
    bool zr = false;
#pragma unroll
    for (int i = 2; i <= 4; i++) {
      if (!zr) {
        mu = fabsf(d[i - 1]) * (mu / (mu + fabsf(e[i - 2])));
        if (mu < sminoa) sminoa = mu;
        if (sminoa == 0.0f) zr = true;
      }
    }
  }
  sminoa = sminoa / sqrtf(4.0f);
  float thresh = fmaxf(TOL4 * sminoa, 96.0f * UNFL4);
  const int maxit = 96;

  int m = 4, iter = 0, oldll = -1, oldm = -1, idir = 0;
  // phase m==4
  for (int g = 0; g < 300; g++) {
    bool act = (m == 4) && (iter <= maxit);
    if (!__any(act)) break;
    if (act) sv_iter<4>(d, e, vt, thresh, m, iter, oldll, oldm, idir);
  }
  // phase m==3
  for (int g = 0; g < 300; g++) {
    bool act = (m == 3) && (iter <= maxit);
    if (!__any(act)) break;
    if (act) sv_iter<3>(d, e, vt, thresh, m, iter, oldll, oldm, idir);
  }
  // phase m==2
  for (int g = 0; g < 300; g++) {
    bool act = (m == 2) && (iter <= maxit);
    if (!__any(act)) break;
    if (act) sv_iter<2>(d, e, vt, thresh, m, iter, oldll, oldm, idir);
  }

  // ---- make nonnegative ----
#pragma unroll
  for (int i = 0; i < 4; i++) {
    if (d[i] < 0.0f) {
      d[i] = -d[i];
#pragma unroll
      for (int k = 1; k < 4; k++) vt[i][k] = -vt[i][k];
    }
  }
  // ---- sort descending (LAPACK tie rule <=), 3 passes ----
  {
    int isub = 1; float smn = d[0];
    if (d[1] <= smn) { isub = 2; smn = d[1]; }
    if (d[2] <= smn) { isub = 3; smn = d[2]; }
    if (d[3] <= smn) { isub = 4; smn = d[3]; }
    if (isub != 4) {
      if (isub == 1) {
        d[0] = d[3];
#pragma unroll
        for (int k = 1; k < 4; k++) { float t = vt[0][k]; vt[0][k] = vt[3][k]; vt[3][k] = t; }
      } else if (isub == 2) {
        d[1] = d[3];
#pragma unroll
        for (int k = 1; k < 4; k++) { float t = vt[1][k]; vt[1][k] = vt[3][k]; vt[3][k] = t; }
      } else {
        d[2] = d[3];
#pragma unroll
        for (int k = 1; k < 4; k++) { float t = vt[2][k]; vt[2][k] = vt[3][k]; vt[3][k] = t; }
      }
      d[3] = smn;
    }
  }
  {
    int isub = 1; float smn = d[0];
    if (d[1] <= smn) { isub = 2; smn = d[1]; }
    if (d[2] <= smn) { isub = 3; smn = d[2]; }
    if (isub != 3) {
      if (isub == 1) {
        d[0] = d[2];
#pragma unroll
        for (int k = 1; k < 4; k++) { float t = vt[0][k]; vt[0][k] = vt[2][k]; vt[2][k] = t; }
      } else {
        d[1] = d[2];
#pragma unroll
        for (int k = 1; k < 4; k++) { float t = vt[1][k]; vt[1][k] = vt[2][k]; vt[2][k] = t; }
      }
      d[2] = smn;
    }
  }
  {
    int isub = 1; float smn = d[0];
    if (d[1] <= smn) { isub = 2; smn = d[1]; }
    if (isub != 2) {
      d[0] = d[1];
#pragma unroll
      for (int k = 1; k < 4; k++) { float t = vt[0][k]; vt[0][k] = vt[1][k]; vt[1][k] = t; }
      d[1] = smn;
    }
  }

  // ---- sormbr: VT := VT * P^T   (i=2 is a taup=0 no-op; then i=1, i=0) ----
#pragma unroll
  for (int r = 0; r < 4; r++) {
    float w = vt[r][2] + vt[r][3] * a[1][3];
    float tw = taup[1] * w;
    vt[r][2] -= tw;
    vt[r][3] -= tw * a[1][3];
  }
#pragma unroll
  for (int r = 0; r < 4; r++) {
    float w = (vt[r][1] + vt[r][2] * a[0][2]) + vt[r][3] * a[0][3];
    float tw = taup[0] * w;
    vt[r][1] -= tw;
    vt[r][2] -= tw * a[0][2];
    vt[r][3] -= tw * a[0][3];
  }

  vec[0] = vt[0][3]; vec[1] = vt[1][3]; vec[2] = vt[2][3]; vec[3] = vt[3][3];
}

// ---------------- Kernel 1: per-batch pose candidates (1 batch / block) ----

__global__ __launch_bounds__(64) void pose_kernel(const float* __restrict__ Fm,
                                                  const float* __restrict__ Km,
                                                  float* __restrict__ ws) {
  int b = blockIdx.x;
  if (threadIdx.x != 0 || b >= NBATCH) return;
  float* wsR = ws;
  float* wsT = ws + 1152;
  float* wsK = ws + 1536;
  int* scores = (int*)(ws + 1664);
  int* counts = (int*)(ws + 1792);
  for (int c = 0; c < 4; c++) scores[b * 4 + c] = 0;
  counts[b] = 0;
  {
#pragma clang fp contract(off)
    const float* F = Fm + b * 9;
    const float* K = Km + b * 9;
    float E[9];
    for (int i = 0; i < 3; i++) for (int l = 0; l < 3; l++) {
      float acc = 0.0f;
      for (int j = 0; j < 3; j++)
        for (int k = 0; k < 3; k++)
          acc += (K[j * 3 + i] * F[j * 3 + k]) * K[k * 3 + l];
      E[i * 3 + l] = acc;
    }
    float U[3][3], VT[3][3];
    gesdd3_pose(E, U, VT);
    float su = (det3f(U) < 0.0f) ? -1.0f : 1.0f;
    float sv = (det3f(VT) < 0.0f) ? -1.0f : 1.0f;
    for (int i = 0; i < 3; i++) for (int j = 0; j < 3; j++) { U[i][j] *= su; VT[i][j] *= sv; }
    float R1[3][3], R2[3][3];
    for (int r = 0; r < 3; r++) {
      float uw0 = U[r][1], uw1 = -U[r][0], uw2 = U[r][2];
      float vw0 = -U[r][1], vw1 = U[r][0];
      for (int c = 0; c < 3; c++) {
        R1[r][c] = (uw0 * VT[c][0] + uw1 * VT[c][1]) + uw2 * VT[c][2];
        R2[r][c] = (vw0 * VT[c][0] + vw1 * VT[c][1]) + uw2 * VT[c][2];
      }
    }
    float t0 = U[0][2], t1 = U[1][2], t2 = U[2][2];
    for (int c = 0; c < 4; c++) {
      const float (*R)[3] = (c < 2) ? R1 : R2;
      float sg = (c & 1) ? -1.0f : 1.0f;
      float* dst = wsR + (b * 4 + c) * 9;
      for (int i = 0; i < 3; i++) for (int j = 0; j < 3; j++) dst[i * 3 + j] = R[i][j];
      float* dt = wsT + (b * 4 + c) * 3;
      dt[0] = sg * t0; dt[1] = sg * t1; dt[2] = sg * t2;
    }
    const float fx = K[0], fy = K[4], cx = K[2], cy = K[5];
    float invfx = 1.0f / fx, invfy = 1.0f / fy;
    wsK[b * 4 + 0] = invfx;
    wsK[b * 4 + 1] = -(invfx * cx);
    wsK[b * 4 + 2] = invfy;
    wsK[b * 4 + 3] = -(invfy * cy);
  }
}

// ---------------- Kernel 2: per-(point, R-pair) cheirality ----------------
// Round-8 structure: 256-thread blocks, LDS staging of R/t/K, LDS histogram.

__global__ __launch_bounds__(256) void score_kernel(const float* __restrict__ pts1,
                                                    const float* __restrict__ pts2,
                                                    const int* __restrict__ bidx,
                                                    float* __restrict__ ws,
                                                    int n_pts) {
  __shared__ float sR[1152];
  __shared__ float sT[384];
  __shared__ float sK[128];
  __shared__ int h01[32], h23[32], hc[32];
  int tid = threadIdx.x;
  for (int i = tid; i < 1152; i += 256) sR[i] = ws[i];
  for (int i = tid; i < 384; i += 256) sT[i] = ws[1152 + i];
  for (int i = tid; i < 128; i += 256) sK[i] = ws[1536 + i];
  if (tid < 32) { h01[tid] = 0; h23[tid] = 0; hc[tid] = 0; }
  __syncthreads();

  int gid = blockIdx.x * 256 + tid;
  int n = gid >> 1, pr = gid & 1;  // pr=0 -> cands {0,1}; pr=1 -> cands {2,3}
  bool active = (n < n_pts);
  bool f0 = false, f1 = false;
  int b = 0;
  if (active) {
    b = bidx[n];
    float x1 = pts1[2 * n], y1 = pts1[2 * n + 1];
    float x2 = pts2[2 * n], y2 = pts2[2 * n + 1];
    float invfx = sK[b * 4 + 0], k02 = sK[b * 4 + 1];
    float invfy = sK[b * 4 + 2], k12 = sK[b * 4 + 3];
    const float* R = sR + (b * 4 + 2 * pr) * 9;
    const float* t = sT + (b * 4 + 2 * pr) * 3;
    float Am[16];
    float row2[4] = { R[6], R[7], R[8], t[2] };
    {
#pragma clang fp contract(off)
      float p1x = invfx * x1 + k02;
      float p1y = invfy * y1 + k12;
      float p2x = invfx * x2 + k02;
      float p2y = invfy * y2 + k12;
      float row0[4] = { R[0], R[1], R[2], t[0] };
      float row1[4] = { R[3], R[4], R[5], t[1] };
      Am[0] = -1.0f; Am[1] = 0.0f; Am[2] = p1x; Am[3] = 0.0f;
      Am[4] = 0.0f; Am[5] = -1.0f; Am[6] = p1y; Am[7] = 0.0f;
#pragma unroll
      for (int k = 0; k < 4; k++) {
        Am[8 + k] = p2x * row2[k] - row0[k];
        Am[12 + k] = p2y * row2[k] - row1[k];
      }
    }
    float vec[4];
    gesdd4_vec(Am, vec);
    {
#pragma clang fp contract(off)
      float v3 = vec[3];
      float X = vec[0] / v3, Y = vec[1] / v3, Z = vec[2] / v3;
      float p0 = row2[0] * X, p1 = row2[1] * Y, p2 = row2[2] * Z;
      float s = (p0 + p1) + p2;
      float t2 = row2[3];
      float z2a = s + t2;        // candidate 2*pr   (+t)
      float z2b = s + (-t2);     // candidate 2*pr+1 (-t)
      bool zpos = (Z > 0.0f);
      f0 = zpos && (z2a > 0.0f);
      f1 = zpos && (z2b > 0.0f);
    }
  }
  if (active) {
    int add = (f0 ? 1 : 0) | (f1 ? (1 << 16) : 0);
    if (add) {
      if (pr == 0) atomicAdd(&h01[b], add);
      else atomicAdd(&h23[b], add);
    }
    if (pr == 0) atomicAdd(&hc[b], 1);
  }
  __syncthreads();
  if (tid < 32) {
    int* scores = (int*)(ws + 1664);
    int* counts = (int*)(ws + 1792);
    int v01 = h01[tid], v23 = h23[tid], vc = hc[tid];
    if (v01 & 0xFFFF) atomicAdd(&scores[tid * 4 + 0], v01 & 0xFFFF);
    if (v01 >> 16) atomicAdd(&scores[tid * 4 + 1], v01 >> 16);
    if (v23 & 0xFFFF) atomicAdd(&scores[tid * 4 + 2], v23 & 0xFFFF);
    if (v23 >> 16) atomicAdd(&scores[tid * 4 + 3], v23 >> 16);
    if (vc) atomicAdd(&counts[tid], vc);
  }
}

// ---------------- Kernel 3: argmax + output ----------------

__global__ __launch_bounds__(64) void final_kernel(const float* __restrict__ ws,
                                                   float* __restrict__ out) {
  int b = threadIdx.x;
  if (b >= NBATCH) return;
  const int* scores = (const int*)(ws + 1664);
  const int* counts = (const int*)(ws + 1792);
  int best = 0, bs = scores[b * 4];
  for (int c = 1; c < 4; c++) {
    int sc = scores[b * 4 + c];
    if (sc > bs) { bs = sc; best = c; }   // np.argmax: first max
  }
  int cnt = counts[b];
  float has = (cnt > 0) ? 1.0f : 0.0f;
  const float* R = ws + (b * 4 + best) * 9;
  const float* t = ws + 1152 + (b * 4 + best) * 3;
  for (int k = 0; k < 9; k++) out[b * 9 + k] = R[k] * has;
  for (int k = 0; k < 3; k++) out[288 + b * 3 + k] = t[k] * has;
  out[384 + b] = (cnt > 0) ? (float)best : 0.0f;
}

// ---------------- Launch ----------------

extern "C" void kernel_launch(void* const* d_in, const int* in_sizes, int n_in,
                              void* d_out, int out_size, void* d_ws, size_t ws_size,
                              hipStream_t stream) {
  (void)n_in; (void)out_size; (void)ws_size;
  const float* F = (const float*)d_in[0];
  const float* K = (const float*)d_in[1];
  const float* p1 = (const float*)d_in[2];
  const float* p2 = (const float*)d_in[3];
  const int* bi = (const int*)d_in[4];
  int n_pts = in_sizes[4];
  float* ws = (float*)d_ws;
  float* out = (float*)d_out;

  pose_kernel<<<NBATCH, 64, 0, stream>>>(F, K, ws);
  int total = n_pts * 2;
  int blocks = (total + 255) / 256;
  score_kernel<<<blocks, 256, 0, stream>>>(p1, p2, bi, ws, n_pts);
  final_kernel<<<1, 64, 0, stream>>>(ws, out);
}